// Round 1
// baseline (45527.719 us; speedup 1.0000x reference)
//
#include <hip/hip_runtime.h>
#include <cstdint>

#define V_SIZE 50257
#define D_DIM  1024
#define H_NUM  16
#define L_NUM  8
#define T_LEN  1024
#define B_NUM  4
#define HD_DIM 64
#define M_ROWS (B_NUM * T_LEN)   // 4096
#define LN_EPS 1e-5f

// ---------------- embedding: x = wte[ctx] + wpe[t] ----------------
__global__ __launch_bounds__(256) void embed_kernel(const int* __restrict__ ctx,
                                                    const float* __restrict__ wte,
                                                    const float* __restrict__ wpe,
                                                    float* __restrict__ x) {
  int i = blockIdx.x * blockDim.x + threadIdx.x;
  if (i >= M_ROWS * D_DIM) return;
  int bt = i / D_DIM, d = i - bt * D_DIM;
  int t = bt & (T_LEN - 1);
  x[i] = wte[(size_t)ctx[bt] * D_DIM + d] + wpe[(size_t)t * D_DIM + d];
}

// ---------------- layernorm: one block (256 thr) per row, D=1024 ----------------
__global__ __launch_bounds__(256) void layernorm_kernel(const float* __restrict__ x,
                                                        const float* __restrict__ g,
                                                        const float* __restrict__ b,
                                                        float* __restrict__ o) {
  int r = blockIdx.x;
  int tid = threadIdx.x;
  const float* row = x + (size_t)r * D_DIM;
  float4 v = *(const float4*)(row + tid * 4);
  float s  = v.x + v.y + v.z + v.w;
  float s2 = v.x * v.x + v.y * v.y + v.z * v.z + v.w * v.w;
  #pragma unroll
  for (int off = 32; off; off >>= 1) {
    s  += __shfl_xor(s, off);
    s2 += __shfl_xor(s2, off);
  }
  __shared__ float a1[4], a2[4];
  int w = tid >> 6, lane = tid & 63;
  if (lane == 0) { a1[w] = s; a2[w] = s2; }
  __syncthreads();
  s  = a1[0] + a1[1] + a1[2] + a1[3];
  s2 = a2[0] + a2[1] + a2[2] + a2[3];
  float mu  = s * (1.0f / D_DIM);
  float var = s2 * (1.0f / D_DIM) - mu * mu;
  float rs  = rsqrtf(var + LN_EPS);
  int d = tid * 4;
  float4 gv = *(const float4*)(g + d);
  float4 bv = *(const float4*)(b + d);
  float4 ov;
  ov.x = (v.x - mu) * rs * gv.x + bv.x;
  ov.y = (v.y - mu) * rs * gv.y + bv.y;
  ov.z = (v.z - mu) * rs * gv.z + bv.z;
  ov.w = (v.w - mu) * rs * gv.w + bv.w;
  *(float4*)(o + (size_t)r * D_DIM + d) = ov;
}

// ---------------- GEMM: C[M,N] = A[M,K] @ W[N,K]^T  (torch Linear) ----------------
// epi: 0 = none, 1 = +R[m,n] residual, 2 = exact GELU
// 64x64 tile, BK=16, 256 threads, 4x4 per-thread microtile. fp32 baseline.
__global__ __launch_bounds__(256) void gemm_kernel(const float* __restrict__ A,
                                                   const float* __restrict__ W,
                                                   const float* R, float* C,
                                                   int M, int N, int K, int epi) {
  __shared__ float As[16][65];
  __shared__ float Ws[16][65];
  int tid = threadIdx.x;
  int row0 = blockIdx.y * 64;
  int col0 = blockIdx.x * 64;
  int tx = tid & 15, ty = tid >> 4;
  int lm = tid >> 2;            // 0..63
  int lk = (tid & 3) << 2;      // 0,4,8,12
  float c[4][4] = {{0.f}};
  for (int k0 = 0; k0 < K; k0 += 16) {
    float4 av = *(const float4*)(A + (size_t)(row0 + lm) * K + k0 + lk);
    int wn = col0 + lm;
    float4 wv = make_float4(0.f, 0.f, 0.f, 0.f);
    if (wn < N) wv = *(const float4*)(W + (size_t)wn * K + k0 + lk);
    As[lk + 0][lm] = av.x; As[lk + 1][lm] = av.y; As[lk + 2][lm] = av.z; As[lk + 3][lm] = av.w;
    Ws[lk + 0][lm] = wv.x; Ws[lk + 1][lm] = wv.y; Ws[lk + 2][lm] = wv.z; Ws[lk + 3][lm] = wv.w;
    __syncthreads();
    #pragma unroll
    for (int k = 0; k < 16; ++k) {
      float a0 = As[k][ty * 4 + 0], a1 = As[k][ty * 4 + 1];
      float a2 = As[k][ty * 4 + 2], a3 = As[k][ty * 4 + 3];
      float b0 = Ws[k][tx * 4 + 0], b1 = Ws[k][tx * 4 + 1];
      float b2 = Ws[k][tx * 4 + 2], b3 = Ws[k][tx * 4 + 3];
      c[0][0] += a0 * b0; c[0][1] += a0 * b1; c[0][2] += a0 * b2; c[0][3] += a0 * b3;
      c[1][0] += a1 * b0; c[1][1] += a1 * b1; c[1][2] += a1 * b2; c[1][3] += a1 * b3;
      c[2][0] += a2 * b0; c[2][1] += a2 * b1; c[2][2] += a2 * b2; c[2][3] += a2 * b3;
      c[3][0] += a3 * b0; c[3][1] += a3 * b1; c[3][2] += a3 * b2; c[3][3] += a3 * b3;
    }
    __syncthreads();
  }
  #pragma unroll
  for (int i = 0; i < 4; ++i) {
    int row = row0 + ty * 4 + i;
    #pragma unroll
    for (int j = 0; j < 4; ++j) {
      int col = col0 + tx * 4 + j;
      if (col < N) {
        float v = c[i][j];
        if (epi == 1)      v += R[(size_t)row * N + col];
        else if (epi == 2) v = 0.5f * v * (1.0f + erff(v * 0.70710678118654752f));
        C[(size_t)row * N + col] = v;
      }
    }
  }
}

// ---------------- causal attention: one wave per (b,h,t), online softmax ----------------
__global__ __launch_bounds__(256) void attn_kernel(const float* __restrict__ qkv,
                                                   float* __restrict__ y) {
  int gid = blockIdx.x * blockDim.x + threadIdx.x;
  int wave = gid >> 6, lane = gid & 63;
  int t  = wave & (T_LEN - 1);
  int bh = wave >> 10;
  int h  = bh & (H_NUM - 1);
  int b  = bh >> 4;
  const size_t row3d = (size_t)3 * D_DIM;
  const float* qp = qkv + (size_t)(b * T_LEN + t) * row3d + h * HD_DIM;
  float q = qp[lane] * 0.125f;   // 1/sqrt(64)
  float m = -1e30f, l = 0.f, acc = 0.f;
  const float* kbase = qkv + (size_t)b * T_LEN * row3d + D_DIM + h * HD_DIM;
  const float* vbase = kbase + D_DIM;
  for (int s = 0; s <= t; ++s) {
    float kv = kbase[(size_t)s * row3d + lane];
    float sc = q * kv;
    #pragma unroll
    for (int off = 32; off; off >>= 1) sc += __shfl_xor(sc, off);
    float vv = vbase[(size_t)s * row3d + lane];
    float mn   = fmaxf(m, sc);
    float corr = __expf(m - mn);
    float p    = __expf(sc - mn);
    l   = l * corr + p;
    acc = acc * corr + p * vv;
    m = mn;
  }
  y[(size_t)(b * T_LEN + t) * D_DIM + h * HD_DIM + lane] = acc / l;
}

// ---------------- loss: per-row logsumexp + NLL ----------------
__global__ __launch_bounds__(256) void loss_rows_kernel(const float* __restrict__ logits,
                                                        const int* __restrict__ tgt,
                                                        float* __restrict__ nll,
                                                        float* __restrict__ vld) {
  int r = blockIdx.x;
  int tid = threadIdx.x;
  const float* row = logits + (size_t)r * V_SIZE;
  float mx = -1e30f;
  for (int i = tid; i < V_SIZE; i += 256) mx = fmaxf(mx, row[i]);
  #pragma unroll
  for (int off = 32; off; off >>= 1) mx = fmaxf(mx, __shfl_xor(mx, off));
  __shared__ float sm[4], ss[4];
  int w = tid >> 6, lane = tid & 63;
  if (lane == 0) sm[w] = mx;
  __syncthreads();
  mx = fmaxf(fmaxf(sm[0], sm[1]), fmaxf(sm[2], sm[3]));
  float se = 0.f;
  for (int i = tid; i < V_SIZE; i += 256) se += expf(row[i] - mx);
  #pragma unroll
  for (int off = 32; off; off >>= 1) se += __shfl_xor(se, off);
  if (lane == 0) ss[w] = se;
  __syncthreads();
  if (tid == 0) {
    se = ss[0] + ss[1] + ss[2] + ss[3];
    int tg = tgt[r];
    if (tg != -1) { nll[r] = mx + logf(se) - row[tg]; vld[r] = 1.0f; }
    else          { nll[r] = 0.f;                     vld[r] = 0.f; }
  }
}

__global__ __launch_bounds__(256) void loss_reduce_kernel(const float* __restrict__ nll,
                                                          const float* __restrict__ vld,
                                                          float* __restrict__ out) {
  int tid = threadIdx.x;
  float s = 0.f, c = 0.f;
  for (int i = tid; i < M_ROWS; i += 256) { s += nll[i]; c += vld[i]; }
  #pragma unroll
  for (int off = 32; off; off >>= 1) { s += __shfl_xor(s, off); c += __shfl_xor(c, off); }
  __shared__ float s1[4], s2[4];
  int w = tid >> 6, lane = tid & 63;
  if (lane == 0) { s1[w] = s; s2[w] = c; }
  __syncthreads();
  if (tid == 0) {
    s = s1[0] + s1[1] + s1[2] + s1[3];
    c = s2[0] + s2[1] + s2[2] + s2[3];
    out[0] = s / fmaxf(c, 1.0f);
  }
}

extern "C" void kernel_launch(void* const* d_in, const int* in_sizes, int n_in,
                              void* d_out, int out_size, void* d_ws, size_t ws_size,
                              hipStream_t stream) {
  const int*   ctx    = (const int*)d_in[0];
  const int*   tgt    = (const int*)d_in[1];
  const float* wte    = (const float*)d_in[2];
  const float* wpe    = (const float*)d_in[3];
  const float* ln1_g  = (const float*)d_in[4];
  const float* ln1_b  = (const float*)d_in[5];
  const float* w_attn = (const float*)d_in[6];
  const float* w_proj = (const float*)d_in[7];
  const float* ln2_g  = (const float*)d_in[8];
  const float* ln2_b  = (const float*)d_in[9];
  const float* w_fc   = (const float*)d_in[10];
  const float* w_out  = (const float*)d_in[11];
  const float* lnf_g  = (const float*)d_in[12];
  const float* lnf_b  = (const float*)d_in[13];

  float* outp   = (float*)d_out;
  float* logits = outp;
  float* loss   = outp + (size_t)M_ROWS * V_SIZE;

  // workspace layout (fp32), total ~168 MB
  float* ws  = (float*)d_ws;
  float* x   = ws;                                  // [M, D]
  float* xn  = x   + (size_t)M_ROWS * D_DIM;        // [M, D]
  float* qkv = xn  + (size_t)M_ROWS * D_DIM;        // [M, 3D]
  float* y   = qkv + (size_t)M_ROWS * 3 * D_DIM;    // [M, D]
  float* h   = y   + (size_t)M_ROWS * D_DIM;        // [M, 4D]
  float* nll = h   + (size_t)M_ROWS * 4 * D_DIM;    // [M]
  float* vld = nll + M_ROWS;                        // [M]

  embed_kernel<<<(M_ROWS * D_DIM + 255) / 256, 256, 0, stream>>>(ctx, wte, wpe, x);

  for (int l = 0; l < L_NUM; ++l) {
    layernorm_kernel<<<M_ROWS, 256, 0, stream>>>(x, ln1_g + l * D_DIM, ln1_b + l * D_DIM, xn);
    gemm_kernel<<<dim3(3 * D_DIM / 64, M_ROWS / 64), 256, 0, stream>>>(
        xn, w_attn + (size_t)l * 3 * D_DIM * D_DIM, nullptr, qkv,
        M_ROWS, 3 * D_DIM, D_DIM, 0);
    attn_kernel<<<(B_NUM * H_NUM * T_LEN * 64) / 256, 256, 0, stream>>>(qkv, y);
    gemm_kernel<<<dim3(D_DIM / 64, M_ROWS / 64), 256, 0, stream>>>(
        y, w_proj + (size_t)l * D_DIM * D_DIM, x, x,
        M_ROWS, D_DIM, D_DIM, 1);
    layernorm_kernel<<<M_ROWS, 256, 0, stream>>>(x, ln2_g + l * D_DIM, ln2_b + l * D_DIM, xn);
    gemm_kernel<<<dim3(4 * D_DIM / 64, M_ROWS / 64), 256, 0, stream>>>(
        xn, w_fc + (size_t)l * 4 * D_DIM * D_DIM, nullptr, h,
        M_ROWS, 4 * D_DIM, D_DIM, 2);
    gemm_kernel<<<dim3(D_DIM / 64, M_ROWS / 64), 256, 0, stream>>>(
        h, w_out + (size_t)l * D_DIM * 4 * D_DIM, x, x,
        M_ROWS, D_DIM, 4 * D_DIM, 1);
  }

  layernorm_kernel<<<M_ROWS, 256, 0, stream>>>(x, lnf_g, lnf_b, xn);
  gemm_kernel<<<dim3((V_SIZE + 63) / 64, M_ROWS / 64), 256, 0, stream>>>(
      xn, wte, nullptr, logits, M_ROWS, V_SIZE, D_DIM, 0);
  loss_rows_kernel<<<M_ROWS, 256, 0, stream>>>(logits, tgt, nll, vld);
  loss_reduce_kernel<<<1, 256, 0, stream>>>(nll, vld, loss);
}

// Round 2
// 26920.316 us; speedup vs baseline: 1.6912x; 1.6912x over previous
//
#include <hip/hip_runtime.h>
#include <cstdint>

#define V_SIZE 50257
#define V_PAD  50304
#define D_DIM  1024
#define H_NUM  16
#define L_NUM  8
#define T_LEN  1024
#define B_NUM  4
#define HD_DIM 64
#define M_ROWS 4096
#define LN_EPS 1e-5f

typedef __attribute__((ext_vector_type(8))) __bf16 bf16x8;
typedef __attribute__((ext_vector_type(4))) float f32x4;
typedef __attribute__((ext_vector_type(8))) unsigned short u16x8;

__device__ __forceinline__ unsigned short f2bf(float f) {
  unsigned u = __builtin_bit_cast(unsigned, f);
  u += 0x7fffu + ((u >> 16) & 1u);   // RNE
  return (unsigned short)(u >> 16);
}

__device__ __forceinline__ void gload_lds16(const void* g, void* l) {
  typedef const __attribute__((address_space(1))) unsigned int* gp_t;
  typedef __attribute__((address_space(3))) unsigned int* lp_t;
  __builtin_amdgcn_global_load_lds((gp_t)g, (lp_t)l, 16, 0, 0);
}

// ---------------- embedding: x = wte[ctx] + wpe[t] (fp32) ----------------
__global__ __launch_bounds__(256) void embed_kernel(const int* __restrict__ ctx,
                                                    const float* __restrict__ wte,
                                                    const float* __restrict__ wpe,
                                                    float* __restrict__ x) {
  int i = blockIdx.x * blockDim.x + threadIdx.x;
  if (i >= M_ROWS * D_DIM) return;
  int bt = i / D_DIM, d = i - bt * D_DIM;
  int t = bt & (T_LEN - 1);
  x[i] = wte[(size_t)ctx[bt] * D_DIM + d] + wpe[(size_t)t * D_DIM + d];
}

// ---------------- fp32 -> bf16 weight conversion (batched, one layer) ----------------
__global__ __launch_bounds__(256) void conv_layer_kernel(const float* __restrict__ wa,
                                                         const float* __restrict__ wp,
                                                         const float* __restrict__ wf,
                                                         const float* __restrict__ wo,
                                                         unsigned short* __restrict__ oa,
                                                         unsigned short* __restrict__ op,
                                                         unsigned short* __restrict__ of,
                                                         unsigned short* __restrict__ oo) {
  long i = (long)(blockIdx.x * 256 + threadIdx.x) * 8;
  const float* src; unsigned short* dst; long off;
  if (i < 3145728L)      { src = wa; dst = oa; off = i; }
  else if (i < 4194304L) { src = wp; dst = op; off = i - 3145728L; }
  else if (i < 8388608L) { src = wf; dst = of; off = i - 4194304L; }
  else                   { src = wo; dst = oo; off = i - 8388608L; }
  float4 v0 = *(const float4*)(src + off);
  float4 v1 = *(const float4*)(src + off + 4);
  u16x8 o;
  o[0] = f2bf(v0.x); o[1] = f2bf(v0.y); o[2] = f2bf(v0.z); o[3] = f2bf(v0.w);
  o[4] = f2bf(v1.x); o[5] = f2bf(v1.y); o[6] = f2bf(v1.z); o[7] = f2bf(v1.w);
  *(u16x8*)(dst + off) = o;
}

// generic converter (wte)
__global__ __launch_bounds__(256) void conv_kernel(const float* __restrict__ in,
                                                   unsigned short* __restrict__ out, long n) {
  long i = (long)(blockIdx.x * 256 + threadIdx.x) * 8;
  if (i >= n) return;
  float4 v0 = *(const float4*)(in + i);
  float4 v1 = *(const float4*)(in + i + 4);
  u16x8 o;
  o[0] = f2bf(v0.x); o[1] = f2bf(v0.y); o[2] = f2bf(v0.z); o[3] = f2bf(v0.w);
  o[4] = f2bf(v1.x); o[5] = f2bf(v1.y); o[6] = f2bf(v1.z); o[7] = f2bf(v1.w);
  *(u16x8*)(out + i) = o;
}

// ---------------- layernorm: fp32 in -> bf16 out, one block per row ----------------
__global__ __launch_bounds__(256) void layernorm_kernel(const float* __restrict__ x,
                                                        const float* __restrict__ g,
                                                        const float* __restrict__ b,
                                                        unsigned short* __restrict__ o) {
  int r = blockIdx.x;
  int tid = threadIdx.x;
  const float* row = x + (size_t)r * D_DIM;
  float4 v = *(const float4*)(row + tid * 4);
  float s  = v.x + v.y + v.z + v.w;
  float s2 = v.x * v.x + v.y * v.y + v.z * v.z + v.w * v.w;
  #pragma unroll
  for (int off = 32; off; off >>= 1) {
    s  += __shfl_xor(s, off);
    s2 += __shfl_xor(s2, off);
  }
  __shared__ float a1[4], a2[4];
  int w = tid >> 6, lane = tid & 63;
  if (lane == 0) { a1[w] = s; a2[w] = s2; }
  __syncthreads();
  s  = a1[0] + a1[1] + a1[2] + a1[3];
  s2 = a2[0] + a2[1] + a2[2] + a2[3];
  float mu  = s * (1.0f / D_DIM);
  float var = s2 * (1.0f / D_DIM) - mu * mu;
  float rs  = rsqrtf(var + LN_EPS);
  int d = tid * 4;
  float4 gv = *(const float4*)(g + d);
  float4 bv = *(const float4*)(b + d);
  ushort4 ov;
  ov.x = f2bf((v.x - mu) * rs * gv.x + bv.x);
  ov.y = f2bf((v.y - mu) * rs * gv.y + bv.y);
  ov.z = f2bf((v.z - mu) * rs * gv.z + bv.z);
  ov.w = f2bf((v.w - mu) * rs * gv.w + bv.w);
  *(ushort4*)(o + (size_t)r * D_DIM + d) = ov;
}

// ---------------- bf16 MFMA GEMM (m97 structure): C[M,N] = A[M,K] @ W[N,K]^T ----------
// 128x128 tile, BK=32, 256 thr (4 waves, 2x2 of 64x64), 16x16x32 MFMA, global_load_lds.
// EPI: 0 = store fp32 (col<nreal guard), 1 = +fp32 residual -> fp32, 2 = exact GELU -> bf16
template<int EPI>
__global__ __launch_bounds__(256) void mfma_gemm(const unsigned short* __restrict__ A,
                                                 const unsigned short* __restrict__ W,
                                                 const float* R, void* Cout,
                                                 int K, int ldc, int nreal) {
  __shared__ unsigned short As[128 * 32];
  __shared__ unsigned short Bs[128 * 32];
  const int tid  = threadIdx.x;
  const int wave = tid >> 6, lane = tid & 63;
  const int wr = wave >> 1, wc = wave & 1;
  const long row0 = (long)blockIdx.y * 128;
  const long col0 = (long)blockIdx.x * 128;
  f32x4 acc[4][4] = {};
  const int frow = lane & 15;         // row within 16x16 fragment
  const int fk   = (lane >> 4) * 8;   // k element offset (8 bf16 per lane)
  // staging: byte b of the 8KB [128][32] bf16 tile -> row=b>>6, k_elem=(b&63)>>1
  const int b0 = wave * 2048 + lane * 16;
  for (int k0 = 0; k0 < K; k0 += 32) {
    #pragma unroll
    for (int c = 0; c < 2; ++c) {
      int b = b0 + c * 1024;
      int r = b >> 6, ke = (b & 63) >> 1;
      gload_lds16(A + (row0 + r) * (long)K + k0 + ke, (char*)As + b);
      gload_lds16(W + (col0 + r) * (long)K + k0 + ke, (char*)Bs + b);
    }
    __syncthreads();   // compiler drains vmcnt(0) before s_barrier
    bf16x8 af[4], bfr[4];
    #pragma unroll
    for (int i = 0; i < 4; ++i)
      af[i] = *(const bf16x8*)(As + (wr * 64 + i * 16 + frow) * 32 + fk);
    #pragma unroll
    for (int j = 0; j < 4; ++j)
      bfr[j] = *(const bf16x8*)(Bs + (wc * 64 + j * 16 + frow) * 32 + fk);
    #pragma unroll
    for (int i = 0; i < 4; ++i)
      #pragma unroll
      for (int j = 0; j < 4; ++j)
        acc[i][j] = __builtin_amdgcn_mfma_f32_16x16x32_bf16(af[i], bfr[j], acc[i][j], 0, 0, 0);
    __syncthreads();
  }
  // epilogue: C/D layout col=lane&15, row=(lane>>4)*4+reg  [verified m89/m91]
  const int crow = (lane >> 4) * 4;
  const int ccol = lane & 15;
  #pragma unroll
  for (int i = 0; i < 4; ++i) {
    #pragma unroll
    for (int r = 0; r < 4; ++r) {
      long row = row0 + wr * 64 + i * 16 + crow + r;
      #pragma unroll
      for (int j = 0; j < 4; ++j) {
        long col = col0 + wc * 64 + j * 16 + ccol;
        float v = acc[i][j][r];
        if (EPI == 0) {
          if (col < nreal) ((float*)Cout)[row * (long)ldc + col] = v;
        } else if (EPI == 1) {
          ((float*)Cout)[row * (long)ldc + col] = v + R[row * (long)ldc + col];
        } else {
          float gl = 0.5f * v * (1.0f + erff(v * 0.70710678118654752440f));
          ((unsigned short*)Cout)[row * (long)ldc + col] = f2bf(gl);
        }
      }
    }
  }
}

// ---------------- causal attention: one wave per (b,h,t), online softmax (fp32) -------
__global__ __launch_bounds__(256) void attn_kernel(const float* __restrict__ qkv,
                                                   unsigned short* __restrict__ y) {
  int gid = blockIdx.x * blockDim.x + threadIdx.x;
  int wave = gid >> 6, lane = gid & 63;
  int t  = wave & (T_LEN - 1);
  int bh = wave >> 10;
  int h  = bh & (H_NUM - 1);
  int b  = bh >> 4;
  const size_t row3d = (size_t)3 * D_DIM;
  const float* qp = qkv + (size_t)(b * T_LEN + t) * row3d + h * HD_DIM;
  float q = qp[lane] * 0.125f;   // 1/sqrt(64)
  float m = -1e30f, l = 0.f, acc = 0.f;
  const float* kbase = qkv + (size_t)b * T_LEN * row3d + D_DIM + h * HD_DIM;
  const float* vbase = kbase + D_DIM;
  for (int s = 0; s <= t; ++s) {
    float kv = kbase[(size_t)s * row3d + lane];
    float sc = q * kv;
    #pragma unroll
    for (int off = 32; off; off >>= 1) sc += __shfl_xor(sc, off);
    float vv = vbase[(size_t)s * row3d + lane];
    float mn   = fmaxf(m, sc);
    float corr = __expf(m - mn);
    float p    = __expf(sc - mn);
    l   = l * corr + p;
    acc = acc * corr + p * vv;
    m = mn;
  }
  y[(size_t)(b * T_LEN + t) * D_DIM + h * HD_DIM + lane] = f2bf(acc / l);
}

// ---------------- loss ----------------
__global__ __launch_bounds__(256) void loss_rows_kernel(const float* __restrict__ logits,
                                                        const int* __restrict__ tgt,
                                                        float* __restrict__ nll,
                                                        float* __restrict__ vld) {
  int r = blockIdx.x;
  int tid = threadIdx.x;
  const float* row = logits + (size_t)r * V_SIZE;
  float mx = -1e30f;
  for (int i = tid; i < V_SIZE; i += 256) mx = fmaxf(mx, row[i]);
  #pragma unroll
  for (int off = 32; off; off >>= 1) mx = fmaxf(mx, __shfl_xor(mx, off));
  __shared__ float sm[4], ss[4];
  int w = tid >> 6, lane = tid & 63;
  if (lane == 0) sm[w] = mx;
  __syncthreads();
  mx = fmaxf(fmaxf(sm[0], sm[1]), fmaxf(sm[2], sm[3]));
  float se = 0.f;
  for (int i = tid; i < V_SIZE; i += 256) se += expf(row[i] - mx);
  #pragma unroll
  for (int off = 32; off; off >>= 1) se += __shfl_xor(se, off);
  if (lane == 0) ss[w] = se;
  __syncthreads();
  if (tid == 0) {
    se = ss[0] + ss[1] + ss[2] + ss[3];
    int tg = tgt[r];
    if (tg != -1) { nll[r] = mx + logf(se) - row[tg]; vld[r] = 1.0f; }
    else          { nll[r] = 0.f;                     vld[r] = 0.f; }
  }
}

__global__ __launch_bounds__(256) void loss_reduce_kernel(const float* __restrict__ nll,
                                                          const float* __restrict__ vld,
                                                          float* __restrict__ out) {
  int tid = threadIdx.x;
  float s = 0.f, c = 0.f;
  for (int i = tid; i < M_ROWS; i += 256) { s += nll[i]; c += vld[i]; }
  #pragma unroll
  for (int off = 32; off; off >>= 1) { s += __shfl_xor(s, off); c += __shfl_xor(c, off); }
  __shared__ float s1[4], s2[4];
  int w = tid >> 6, lane = tid & 63;
  if (lane == 0) { s1[w] = s; s2[w] = c; }
  __syncthreads();
  if (tid == 0) {
    s = s1[0] + s1[1] + s1[2] + s1[3];
    c = s2[0] + s2[1] + s2[2] + s2[3];
    out[0] = s / fmaxf(c, 1.0f);
  }
}

extern "C" void kernel_launch(void* const* d_in, const int* in_sizes, int n_in,
                              void* d_out, int out_size, void* d_ws, size_t ws_size,
                              hipStream_t stream) {
  const int*   ctx    = (const int*)d_in[0];
  const int*   tgt    = (const int*)d_in[1];
  const float* wte    = (const float*)d_in[2];
  const float* wpe    = (const float*)d_in[3];
  const float* ln1_g  = (const float*)d_in[4];
  const float* ln1_b  = (const float*)d_in[5];
  const float* w_attn = (const float*)d_in[6];
  const float* w_proj = (const float*)d_in[7];
  const float* ln2_g  = (const float*)d_in[8];
  const float* ln2_b  = (const float*)d_in[9];
  const float* w_fc   = (const float*)d_in[10];
  const float* w_out  = (const float*)d_in[11];
  const float* lnf_g  = (const float*)d_in[12];
  const float* lnf_b  = (const float*)d_in[13];

  float* outp   = (float*)d_out;
  float* logits = outp;
  float* loss   = outp + (size_t)M_ROWS * V_SIZE;

  // ---- workspace layout (bytes), total ~142.7 MB ----
  char* ws = (char*)d_ws;
  float*          x      = (float*)(ws + 0);                    // 16.78 MB fp32 [4096][1024]
  unsigned short* xn     = (unsigned short*)(ws + 16777216);    //  8.39 MB bf16 [4096][1024]
  // union region (layer-phase buffers; wte_bf16 aliases it after the layer loop)
  float*          qkv    = (float*)(ws + 25165824);             // 50.33 MB fp32 [4096][3072]
  unsigned short* y      = (unsigned short*)(ws + 75497472);    //  8.39 MB bf16
  unsigned short* h      = (unsigned short*)(ws + 83886080);    // 33.55 MB bf16 [4096][4096]
  unsigned short* wa_bf  = (unsigned short*)(ws + 117440512);   //  6.29 MB
  unsigned short* wp_bf  = (unsigned short*)(ws + 123731968);   //  2.10 MB
  unsigned short* wf_bf  = (unsigned short*)(ws + 125829120);   //  8.39 MB
  unsigned short* wo_bf  = (unsigned short*)(ws + 134217728);   //  8.39 MB
  unsigned short* wte_bf = (unsigned short*)(ws + 25165824);    // 103.0 MB bf16 [50304][1024] (alias)
  float*          nll    = (float*)(ws + 142606336);
  float*          vld    = (float*)(ws + 142622720);

  embed_kernel<<<(M_ROWS * D_DIM + 255) / 256, 256, 0, stream>>>(ctx, wte, wpe, x);

  for (int l = 0; l < L_NUM; ++l) {
    conv_layer_kernel<<<6144, 256, 0, stream>>>(
        w_attn + (size_t)l * 3 * D_DIM * D_DIM, w_proj + (size_t)l * D_DIM * D_DIM,
        w_fc + (size_t)l * 4 * D_DIM * D_DIM, w_out + (size_t)l * D_DIM * 4 * D_DIM,
        wa_bf, wp_bf, wf_bf, wo_bf);
    layernorm_kernel<<<M_ROWS, 256, 0, stream>>>(x, ln1_g + l * D_DIM, ln1_b + l * D_DIM, xn);
    mfma_gemm<0><<<dim3(3 * D_DIM / 128, M_ROWS / 128), 256, 0, stream>>>(
        xn, wa_bf, nullptr, qkv, D_DIM, 3 * D_DIM, 3 * D_DIM);
    attn_kernel<<<(B_NUM * H_NUM * T_LEN * 64) / 256, 256, 0, stream>>>(qkv, y);
    mfma_gemm<1><<<dim3(D_DIM / 128, M_ROWS / 128), 256, 0, stream>>>(
        y, wp_bf, x, x, D_DIM, D_DIM, D_DIM);
    layernorm_kernel<<<M_ROWS, 256, 0, stream>>>(x, ln2_g + l * D_DIM, ln2_b + l * D_DIM, xn);
    mfma_gemm<2><<<dim3(4 * D_DIM / 128, M_ROWS / 128), 256, 0, stream>>>(
        xn, wf_bf, nullptr, h, D_DIM, 4 * D_DIM, 4 * D_DIM);
    mfma_gemm<1><<<dim3(D_DIM / 128, M_ROWS / 128), 256, 0, stream>>>(
        h, wo_bf, x, x, 4 * D_DIM, D_DIM, D_DIM);
  }

  layernorm_kernel<<<M_ROWS, 256, 0, stream>>>(x, lnf_g, lnf_b, xn);
  // convert wte -> bf16 (aliases dead layer buffers), zero pad rows
  conv_kernel<<<25129, 256, 0, stream>>>(wte, wte_bf, (long)V_SIZE * D_DIM);
  hipMemsetAsync(wte_bf + (size_t)V_SIZE * D_DIM, 0,
                 (size_t)(V_PAD - V_SIZE) * D_DIM * sizeof(unsigned short), stream);
  mfma_gemm<0><<<dim3(V_PAD / 128, M_ROWS / 128), 256, 0, stream>>>(
      xn, wte_bf, nullptr, logits, D_DIM, V_SIZE, V_SIZE);
  loss_rows_kernel<<<M_ROWS, 256, 0, stream>>>(logits, tgt, nll, vld);
  loss_reduce_kernel<<<1, 256, 0, stream>>>(nll, vld, loss);
}

// Round 3
// 3979.981 us; speedup vs baseline: 11.4392x; 6.7639x over previous
//
#include <hip/hip_runtime.h>
#include <cstdint>

#define V_SIZE 50257
#define V_PAD  50304
#define D_DIM  1024
#define H_NUM  16
#define L_NUM  8
#define T_LEN  1024
#define B_NUM  4
#define HD_DIM 64
#define M_ROWS 4096
#define LN_EPS 1e-5f

typedef __attribute__((ext_vector_type(8))) __bf16 bf16x8;
typedef __attribute__((ext_vector_type(4))) float f32x4;
typedef __attribute__((ext_vector_type(8))) unsigned short u16x8;

__device__ __forceinline__ unsigned short f2bf(float f) {
  unsigned u = __builtin_bit_cast(unsigned, f);
  u += 0x7fffu + ((u >> 16) & 1u);   // RNE
  return (unsigned short)(u >> 16);
}

__device__ __forceinline__ void gload_lds16(const void* g, void* l) {
  typedef const __attribute__((address_space(1))) unsigned int* gp_t;
  typedef __attribute__((address_space(3))) unsigned int* lp_t;
  __builtin_amdgcn_global_load_lds((gp_t)g, (lp_t)l, 16, 0, 0);
}

// ---------------- embedding ----------------
__global__ __launch_bounds__(256) void embed_kernel(const int* __restrict__ ctx,
                                                    const float* __restrict__ wte,
                                                    const float* __restrict__ wpe,
                                                    float* __restrict__ x) {
  int i = blockIdx.x * blockDim.x + threadIdx.x;
  if (i >= M_ROWS * D_DIM) return;
  int bt = i / D_DIM, d = i - bt * D_DIM;
  int t = bt & (T_LEN - 1);
  x[i] = wte[(size_t)ctx[bt] * D_DIM + d] + wpe[(size_t)t * D_DIM + d];
}

// ---------------- fp32 -> bf16 weight conversion ----------------
__global__ __launch_bounds__(256) void conv_layer_kernel(const float* __restrict__ wa,
                                                         const float* __restrict__ wp,
                                                         const float* __restrict__ wf,
                                                         const float* __restrict__ wo,
                                                         unsigned short* __restrict__ oa,
                                                         unsigned short* __restrict__ op,
                                                         unsigned short* __restrict__ of,
                                                         unsigned short* __restrict__ oo) {
  long i = (long)(blockIdx.x * 256 + threadIdx.x) * 8;
  const float* src; unsigned short* dst; long off;
  if (i < 3145728L)      { src = wa; dst = oa; off = i; }
  else if (i < 4194304L) { src = wp; dst = op; off = i - 3145728L; }
  else if (i < 8388608L) { src = wf; dst = of; off = i - 4194304L; }
  else                   { src = wo; dst = oo; off = i - 8388608L; }
  float4 v0 = *(const float4*)(src + off);
  float4 v1 = *(const float4*)(src + off + 4);
  u16x8 o;
  o[0] = f2bf(v0.x); o[1] = f2bf(v0.y); o[2] = f2bf(v0.z); o[3] = f2bf(v0.w);
  o[4] = f2bf(v1.x); o[5] = f2bf(v1.y); o[6] = f2bf(v1.z); o[7] = f2bf(v1.w);
  *(u16x8*)(dst + off) = o;
}

__global__ __launch_bounds__(256) void conv_kernel(const float* __restrict__ in,
                                                   unsigned short* __restrict__ out, long n) {
  long i = (long)(blockIdx.x * 256 + threadIdx.x) * 8;
  if (i >= n) return;
  float4 v0 = *(const float4*)(in + i);
  float4 v1 = *(const float4*)(in + i + 4);
  u16x8 o;
  o[0] = f2bf(v0.x); o[1] = f2bf(v0.y); o[2] = f2bf(v0.z); o[3] = f2bf(v0.w);
  o[4] = f2bf(v1.x); o[5] = f2bf(v1.y); o[6] = f2bf(v1.z); o[7] = f2bf(v1.w);
  *(u16x8*)(out + i) = o;
}

// ---------------- layernorm: fp32 in -> bf16 out ----------------
__global__ __launch_bounds__(256) void layernorm_kernel(const float* __restrict__ x,
                                                        const float* __restrict__ g,
                                                        const float* __restrict__ b,
                                                        unsigned short* __restrict__ o) {
  int r = blockIdx.x;
  int tid = threadIdx.x;
  const float* row = x + (size_t)r * D_DIM;
  float4 v = *(const float4*)(row + tid * 4);
  float s  = v.x + v.y + v.z + v.w;
  float s2 = v.x * v.x + v.y * v.y + v.z * v.z + v.w * v.w;
  #pragma unroll
  for (int off = 32; off; off >>= 1) {
    s  += __shfl_xor(s, off);
    s2 += __shfl_xor(s2, off);
  }
  __shared__ float a1[4], a2[4];
  int w = tid >> 6, lane = tid & 63;
  if (lane == 0) { a1[w] = s; a2[w] = s2; }
  __syncthreads();
  s  = a1[0] + a1[1] + a1[2] + a1[3];
  s2 = a2[0] + a2[1] + a2[2] + a2[3];
  float mu  = s * (1.0f / D_DIM);
  float var = s2 * (1.0f / D_DIM) - mu * mu;
  float rs  = rsqrtf(var + LN_EPS);
  int d = tid * 4;
  float4 gv = *(const float4*)(g + d);
  float4 bv = *(const float4*)(b + d);
  ushort4 ov;
  ov.x = f2bf((v.x - mu) * rs * gv.x + bv.x);
  ov.y = f2bf((v.y - mu) * rs * gv.y + bv.y);
  ov.z = f2bf((v.z - mu) * rs * gv.z + bv.z);
  ov.w = f2bf((v.w - mu) * rs * gv.w + bv.w);
  *(ushort4*)(o + (size_t)r * D_DIM + d) = ov;
}

// ---------------- bf16 MFMA GEMM (m97 structure): C = A @ W^T ----------
// EPI: 0 = fp32 store (col<nreal guard), 1 = +fp32 residual -> fp32,
//      2 = exact GELU -> bf16, 3 = bf16 store
template<int EPI>
__global__ __launch_bounds__(256) void mfma_gemm(const unsigned short* __restrict__ A,
                                                 const unsigned short* __restrict__ W,
                                                 const float* R, void* Cout,
                                                 int K, int ldc, int nreal) {
  __shared__ unsigned short As[128 * 32];
  __shared__ unsigned short Bs[128 * 32];
  const int tid  = threadIdx.x;
  const int wave = tid >> 6, lane = tid & 63;
  const int wr = wave >> 1, wc = wave & 1;
  const long row0 = (long)blockIdx.y * 128;
  const long col0 = (long)blockIdx.x * 128;
  f32x4 acc[4][4] = {};
  const int frow = lane & 15;
  const int fk   = (lane >> 4) * 8;
  const int b0 = wave * 2048 + lane * 16;
  for (int k0 = 0; k0 < K; k0 += 32) {
    #pragma unroll
    for (int c = 0; c < 2; ++c) {
      int b = b0 + c * 1024;
      int r = b >> 6, ke = (b & 63) >> 1;
      gload_lds16(A + (row0 + r) * (long)K + k0 + ke, (char*)As + b);
      gload_lds16(W + (col0 + r) * (long)K + k0 + ke, (char*)Bs + b);
    }
    __syncthreads();
    bf16x8 af[4], bfr[4];
    #pragma unroll
    for (int i = 0; i < 4; ++i)
      af[i] = *(const bf16x8*)(As + (wr * 64 + i * 16 + frow) * 32 + fk);
    #pragma unroll
    for (int j = 0; j < 4; ++j)
      bfr[j] = *(const bf16x8*)(Bs + (wc * 64 + j * 16 + frow) * 32 + fk);
    #pragma unroll
    for (int i = 0; i < 4; ++i)
      #pragma unroll
      for (int j = 0; j < 4; ++j)
        acc[i][j] = __builtin_amdgcn_mfma_f32_16x16x32_bf16(af[i], bfr[j], acc[i][j], 0, 0, 0);
    __syncthreads();
  }
  const int crow = (lane >> 4) * 4;
  const int ccol = lane & 15;
  #pragma unroll
  for (int i = 0; i < 4; ++i) {
    #pragma unroll
    for (int r = 0; r < 4; ++r) {
      long row = row0 + wr * 64 + i * 16 + crow + r;
      #pragma unroll
      for (int j = 0; j < 4; ++j) {
        long col = col0 + wc * 64 + j * 16 + ccol;
        float v = acc[i][j][r];
        if (EPI == 0) {
          if (col < nreal) ((float*)Cout)[row * (long)ldc + col] = v;
        } else if (EPI == 1) {
          ((float*)Cout)[row * (long)ldc + col] = v + R[row * (long)ldc + col];
        } else if (EPI == 2) {
          float gl = 0.5f * v * (1.0f + erff(v * 0.70710678118654752440f));
          ((unsigned short*)Cout)[row * (long)ldc + col] = f2bf(gl);
        } else {
          ((unsigned short*)Cout)[row * (long)ldc + col] = f2bf(v);
        }
      }
    }
  }
}

// ---------------- MFMA flash attention ----------------
// grid (T/64, B*H), 256 thr = 4 waves. Wave w owns queries q0+w*16..+15.
// K staged [64 keys][64 d] (swizzled); V staged transposed [64 d][64 keys] (swizzled);
// P (bf16) wave-private LDS [16 q][64 k] (swizzled). All swizzles: byte ^= (row&7)<<4.
__global__ __launch_bounds__(256) void flash_attn_kernel(const unsigned short* __restrict__ qkv,
                                                         unsigned short* __restrict__ y) {
  __shared__ unsigned short Kls[64 * 64];
  __shared__ unsigned short Vtls[64 * 64];
  __shared__ unsigned short Pls[4][16 * 64];
  const int tid = threadIdx.x, wave = tid >> 6, lane = tid & 63;
  const int qt = blockIdx.x;
  const int h = blockIdx.y & (H_NUM - 1), b = blockIdx.y >> 4;
  const int q0 = qt * 64;
  const int lhi = lane >> 4, llo = lane & 15;

  // Q fragments (A-operand): row = llo, k = lhi*8..+7
  const int qrow = q0 + wave * 16 + llo;
  const unsigned short* qptr =
      qkv + ((size_t)(b * T_LEN + qrow)) * 3072 + h * HD_DIM + lhi * 8;
  const bf16x8 qa0 = *(const bf16x8*)qptr;
  const bf16x8 qa1 = *(const bf16x8*)(qptr + 32);

  f32x4 o[4] = {};                    // o[dt]: row q=lhi*4+r, col d=dt*16+llo
  float m[4] = {-1e30f, -1e30f, -1e30f, -1e30f};
  float l[4] = {0.f, 0.f, 0.f, 0.f};

  const unsigned short* kg = qkv + (size_t)b * T_LEN * 3072 + D_DIM + h * HD_DIM;
  const unsigned short* vg = kg + D_DIM;

  // staging indices
  const int krow = tid >> 2, kcol = (tid & 3) * 16;        // K: 64 rows x 4 thr x 32B
  const int vs0 = (tid >> 3) * 2, vd0 = (tid & 7) * 8;     // V: 2 rows x 8 bf16 per thr

  const int ntiles = qt + 1;
  for (int st = 0; st < ntiles; ++st) {
    const int s0 = st * 64;
    // ---- stage K [key][d] swizzled ----
    {
      const unsigned short* src = kg + (size_t)(s0 + krow) * 3072 + kcol;
      u16x8 a = *(const u16x8*)src;
      u16x8 c = *(const u16x8*)(src + 8);
      int base = krow * 128 + kcol * 2;
      int sw = (krow & 7) << 4;
      *(u16x8*)((char*)Kls + ((base) ^ sw))      = a;
      *(u16x8*)((char*)Kls + ((base + 16) ^ sw)) = c;
    }
    // ---- stage V transposed: Vt[d][s] swizzled ----
    {
      const unsigned short* src = vg + (size_t)(s0 + vs0) * 3072 + vd0;
      u16x8 a = *(const u16x8*)src;
      u16x8 c = *(const u16x8*)(src + 3072);
      #pragma unroll
      for (int j = 0; j < 8; ++j) {
        int d = vd0 + j;
        unsigned val = (unsigned)a[j] | ((unsigned)c[j] << 16);
        *(unsigned*)((char*)Vtls + ((d * 128 + vs0 * 2) ^ ((d & 7) << 4))) = val;
      }
    }
    __syncthreads();

    // ---- QK^T: S[16q x 64k] in 4 accumulators ----
    f32x4 s_acc[4] = {};
    #pragma unroll
    for (int kt = 0; kt < 4; ++kt) {
      int kr = kt * 16 + llo;
      int sw = (kr & 7) << 4;
      bf16x8 kb0 = *(const bf16x8*)((char*)Kls + ((kr * 128 + lhi * 16) ^ sw));
      bf16x8 kb1 = *(const bf16x8*)((char*)Kls + ((kr * 128 + 64 + lhi * 16) ^ sw));
      s_acc[kt] = __builtin_amdgcn_mfma_f32_16x16x32_bf16(qa0, kb0, s_acc[kt], 0, 0, 0);
      s_acc[kt] = __builtin_amdgcn_mfma_f32_16x16x32_bf16(qa1, kb1, s_acc[kt], 0, 0, 0);
    }

    // ---- mask + online softmax (per q-row stats across 16 key-lanes) ----
    float p[4][4];    // [kt][r]
    float tmax[4] = {-1e30f, -1e30f, -1e30f, -1e30f};
    const int qg = q0 + wave * 16 + lhi * 4;
    #pragma unroll
    for (int kt = 0; kt < 4; ++kt) {
      int ks = s0 + kt * 16 + llo;
      #pragma unroll
      for (int r = 0; r < 4; ++r) {
        float sv = (ks <= qg + r) ? s_acc[kt][r] * 0.125f : -1e30f;
        p[kt][r] = sv;
        tmax[r] = fmaxf(tmax[r], sv);
      }
    }
    #pragma unroll
    for (int r = 0; r < 4; ++r) {
      #pragma unroll
      for (int off = 1; off < 16; off <<= 1)
        tmax[r] = fmaxf(tmax[r], __shfl_xor(tmax[r], off));
      float mn = fmaxf(m[r], tmax[r]);
      float corr = __expf(m[r] - mn);
      m[r] = mn;
      float ps = 0.f;
      #pragma unroll
      for (int kt = 0; kt < 4; ++kt) {
        p[kt][r] = __expf(p[kt][r] - mn);
        ps += p[kt][r];
      }
      #pragma unroll
      for (int off = 1; off < 16; off <<= 1)
        ps += __shfl_xor(ps, off);
      l[r] = l[r] * corr + ps;
      #pragma unroll
      for (int dt = 0; dt < 4; ++dt) o[dt][r] *= corr;
    }

    // ---- write P (bf16) to wave-private LDS [q][k], swizzled ----
    unsigned short* pw = Pls[wave];
    #pragma unroll
    for (int r = 0; r < 4; ++r) {
      int q = lhi * 4 + r;
      int sw = (q & 7) << 4;
      #pragma unroll
      for (int kt = 0; kt < 4; ++kt) {
        int k = kt * 16 + llo;
        *(unsigned short*)((char*)pw + ((q * 128 + k * 2) ^ sw)) = f2bf(p[kt][r]);
      }
    }
    asm volatile("s_waitcnt lgkmcnt(0)" ::: "memory");

    // ---- PV: O += P[16x64] @ V[64x64] ----
    int psw = (llo & 7) << 4;
    bf16x8 pa0 = *(const bf16x8*)((char*)pw + ((llo * 128 + lhi * 16) ^ psw));
    bf16x8 pa1 = *(const bf16x8*)((char*)pw + ((llo * 128 + 64 + lhi * 16) ^ psw));
    #pragma unroll
    for (int dt = 0; dt < 4; ++dt) {
      int vr = dt * 16 + llo;
      int sw = (vr & 7) << 4;
      bf16x8 vb0 = *(const bf16x8*)((char*)Vtls + ((vr * 128 + lhi * 16) ^ sw));
      bf16x8 vb1 = *(const bf16x8*)((char*)Vtls + ((vr * 128 + 64 + lhi * 16) ^ sw));
      o[dt] = __builtin_amdgcn_mfma_f32_16x16x32_bf16(pa0, vb0, o[dt], 0, 0, 0);
      o[dt] = __builtin_amdgcn_mfma_f32_16x16x32_bf16(pa1, vb1, o[dt], 0, 0, 0);
    }
    __syncthreads();
  }

  // ---- epilogue: y[q][h*64+d] = o/l ----
  #pragma unroll
  for (int r = 0; r < 4; ++r) {
    long row = q0 + wave * 16 + lhi * 4 + r;
    float inv = 1.0f / l[r];
    #pragma unroll
    for (int dt = 0; dt < 4; ++dt) {
      long col = h * HD_DIM + dt * 16 + llo;
      y[(row + (size_t)b * T_LEN) * D_DIM + col] = f2bf(o[dt][r] * inv);
    }
  }
}

// ---------------- loss ----------------
__global__ __launch_bounds__(256) void loss_rows_kernel(const float* __restrict__ logits,
                                                        const int* __restrict__ tgt,
                                                        float* __restrict__ nll,
                                                        float* __restrict__ vld) {
  int r = blockIdx.x;
  int tid = threadIdx.x;
  const float* row = logits + (size_t)r * V_SIZE;
  float mx = -1e30f;
  for (int i = tid; i < V_SIZE; i += 256) mx = fmaxf(mx, row[i]);
  #pragma unroll
  for (int off = 32; off; off >>= 1) mx = fmaxf(mx, __shfl_xor(mx, off));
  __shared__ float sm[4], ss[4];
  int w = tid >> 6, lane = tid & 63;
  if (lane == 0) sm[w] = mx;
  __syncthreads();
  mx = fmaxf(fmaxf(sm[0], sm[1]), fmaxf(sm[2], sm[3]));
  float se = 0.f;
  for (int i = tid; i < V_SIZE; i += 256) se += expf(row[i] - mx);
  #pragma unroll
  for (int off = 32; off; off >>= 1) se += __shfl_xor(se, off);
  if (lane == 0) ss[w] = se;
  __syncthreads();
  if (tid == 0) {
    se = ss[0] + ss[1] + ss[2] + ss[3];
    int tg = tgt[r];
    if (tg != -1) { nll[r] = mx + logf(se) - row[tg]; vld[r] = 1.0f; }
    else          { nll[r] = 0.f;                     vld[r] = 0.f; }
  }
}

__global__ __launch_bounds__(256) void loss_reduce_kernel(const float* __restrict__ nll,
                                                          const float* __restrict__ vld,
                                                          float* __restrict__ out) {
  int tid = threadIdx.x;
  float s = 0.f, c = 0.f;
  for (int i = tid; i < M_ROWS; i += 256) { s += nll[i]; c += vld[i]; }
  #pragma unroll
  for (int off = 32; off; off >>= 1) { s += __shfl_xor(s, off); c += __shfl_xor(c, off); }
  __shared__ float s1[4], s2[4];
  int w = tid >> 6, lane = tid & 63;
  if (lane == 0) { s1[w] = s; s2[w] = c; }
  __syncthreads();
  if (tid == 0) {
    s = s1[0] + s1[1] + s1[2] + s1[3];
    c = s2[0] + s2[1] + s2[2] + s2[3];
    out[0] = s / fmaxf(c, 1.0f);
  }
}

extern "C" void kernel_launch(void* const* d_in, const int* in_sizes, int n_in,
                              void* d_out, int out_size, void* d_ws, size_t ws_size,
                              hipStream_t stream) {
  const int*   ctx    = (const int*)d_in[0];
  const int*   tgt    = (const int*)d_in[1];
  const float* wte    = (const float*)d_in[2];
  const float* wpe    = (const float*)d_in[3];
  const float* ln1_g  = (const float*)d_in[4];
  const float* ln1_b  = (const float*)d_in[5];
  const float* w_attn = (const float*)d_in[6];
  const float* w_proj = (const float*)d_in[7];
  const float* ln2_g  = (const float*)d_in[8];
  const float* ln2_b  = (const float*)d_in[9];
  const float* w_fc   = (const float*)d_in[10];
  const float* w_out  = (const float*)d_in[11];
  const float* lnf_g  = (const float*)d_in[12];
  const float* lnf_b  = (const float*)d_in[13];

  float* outp   = (float*)d_out;
  float* logits = outp;
  float* loss   = outp + (size_t)M_ROWS * V_SIZE;

  // ---- workspace layout (bytes), max ~128.3 MB ----
  char* ws = (char*)d_ws;
  float*          x      = (float*)(ws + 0);                    // fp32 [4096][1024]
  unsigned short* xn     = (unsigned short*)(ws + 16777216);    // bf16 [4096][1024]
  unsigned short* qkv    = (unsigned short*)(ws + 25165824);    // bf16 [4096][3072]
  unsigned short* y      = (unsigned short*)(ws + 50331648);    // bf16 [4096][1024]
  unsigned short* h      = (unsigned short*)(ws + 58720256);    // bf16 [4096][4096]
  unsigned short* wa_bf  = (unsigned short*)(ws + 92274688);
  unsigned short* wp_bf  = (unsigned short*)(ws + 98566144);
  unsigned short* wf_bf  = (unsigned short*)(ws + 100663296);
  unsigned short* wo_bf  = (unsigned short*)(ws + 109051904);
  unsigned short* wte_bf = (unsigned short*)(ws + 25165824);    // alias (post-loop) [50304][1024]
  float*          nll    = (float*)(ws + 128188416);
  float*          vld    = (float*)(ws + 128204800);

  embed_kernel<<<(M_ROWS * D_DIM + 255) / 256, 256, 0, stream>>>(ctx, wte, wpe, x);

  for (int l = 0; l < L_NUM; ++l) {
    conv_layer_kernel<<<6144, 256, 0, stream>>>(
        w_attn + (size_t)l * 3 * D_DIM * D_DIM, w_proj + (size_t)l * D_DIM * D_DIM,
        w_fc + (size_t)l * 4 * D_DIM * D_DIM, w_out + (size_t)l * D_DIM * 4 * D_DIM,
        wa_bf, wp_bf, wf_bf, wo_bf);
    layernorm_kernel<<<M_ROWS, 256, 0, stream>>>(x, ln1_g + l * D_DIM, ln1_b + l * D_DIM, xn);
    mfma_gemm<3><<<dim3(3 * D_DIM / 128, M_ROWS / 128), 256, 0, stream>>>(
        xn, wa_bf, nullptr, qkv, D_DIM, 3 * D_DIM, 3 * D_DIM);
    flash_attn_kernel<<<dim3(T_LEN / 64, B_NUM * H_NUM), 256, 0, stream>>>(qkv, y);
    mfma_gemm<1><<<dim3(D_DIM / 128, M_ROWS / 128), 256, 0, stream>>>(
        y, wp_bf, x, x, D_DIM, D_DIM, D_DIM);
    layernorm_kernel<<<M_ROWS, 256, 0, stream>>>(x, ln2_g + l * D_DIM, ln2_b + l * D_DIM, xn);
    mfma_gemm<2><<<dim3(4 * D_DIM / 128, M_ROWS / 128), 256, 0, stream>>>(
        xn, wf_bf, nullptr, h, D_DIM, 4 * D_DIM, 4 * D_DIM);
    mfma_gemm<1><<<dim3(D_DIM / 128, M_ROWS / 128), 256, 0, stream>>>(
        h, wo_bf, x, x, 4 * D_DIM, D_DIM, D_DIM);
  }

  layernorm_kernel<<<M_ROWS, 256, 0, stream>>>(x, lnf_g, lnf_b, xn);
  conv_kernel<<<25129, 256, 0, stream>>>(wte, wte_bf, (long)V_SIZE * D_DIM);
  hipMemsetAsync(wte_bf + (size_t)V_SIZE * D_DIM, 0,
                 (size_t)(V_PAD - V_SIZE) * D_DIM * sizeof(unsigned short), stream);
  mfma_gemm<0><<<dim3(V_PAD / 128, M_ROWS / 128), 256, 0, stream>>>(
      xn, wte_bf, nullptr, logits, D_DIM, V_SIZE, V_SIZE);
  loss_rows_kernel<<<M_ROWS, 256, 0, stream>>>(logits, tgt, nll, vld);
  loss_reduce_kernel<<<1, 256, 0, stream>>>(nll, vld, loss);
}

// Round 5
// 3655.756 us; speedup vs baseline: 12.4537x; 1.0887x over previous
//
#include <hip/hip_runtime.h>
#include <cstdint>

#define V_SIZE 50257
#define V_PAD  50432            // 197 * 256
#define D_DIM  1024
#define H_NUM  16
#define L_NUM  8
#define T_LEN  1024
#define B_NUM  4
#define HD_DIM 64
#define M_ROWS 4096
#define LN_EPS 1e-5f

typedef __attribute__((ext_vector_type(8))) __bf16 bf16x8;
typedef __attribute__((ext_vector_type(4))) float f32x4;
typedef __attribute__((ext_vector_type(8))) unsigned short u16x8;

__device__ __forceinline__ unsigned short f2bf(float f) {
  unsigned u = __builtin_bit_cast(unsigned, f);
  u += 0x7fffu + ((u >> 16) & 1u);   // RNE
  return (unsigned short)(u >> 16);
}

__device__ __forceinline__ void gload_lds16(const void* g, void* l) {
  typedef const __attribute__((address_space(1))) unsigned int* gp_t;
  typedef __attribute__((address_space(3))) unsigned int* lp_t;
  __builtin_amdgcn_global_load_lds((gp_t)g, (lp_t)l, 16, 0, 0);
}

#define BARSB() { __builtin_amdgcn_s_barrier(); __builtin_amdgcn_sched_barrier(0); }
#define LGKM0() { asm volatile("s_waitcnt lgkmcnt(0)" ::: "memory"); __builtin_amdgcn_sched_barrier(0); }

// ---------------- embedding ----------------
__global__ __launch_bounds__(256) void embed_kernel(const int* __restrict__ ctx,
                                                    const float* __restrict__ wte,
                                                    const float* __restrict__ wpe,
                                                    float* __restrict__ x) {
  int i = blockIdx.x * blockDim.x + threadIdx.x;
  if (i >= M_ROWS * D_DIM) return;
  int bt = i / D_DIM, d = i - bt * D_DIM;
  int t = bt & (T_LEN - 1);
  x[i] = wte[(size_t)ctx[bt] * D_DIM + d] + wpe[(size_t)t * D_DIM + d];
}

// ---------------- fp32 -> bf16 weight conversion ----------------
__global__ __launch_bounds__(256) void conv_layer_kernel(const float* __restrict__ wa,
                                                         const float* __restrict__ wp,
                                                         const float* __restrict__ wf,
                                                         const float* __restrict__ wo,
                                                         unsigned short* __restrict__ oa,
                                                         unsigned short* __restrict__ op,
                                                         unsigned short* __restrict__ of,
                                                         unsigned short* __restrict__ oo) {
  long i = (long)(blockIdx.x * 256 + threadIdx.x) * 8;
  const float* src; unsigned short* dst; long off;
  if (i < 3145728L)      { src = wa; dst = oa; off = i; }
  else if (i < 4194304L) { src = wp; dst = op; off = i - 3145728L; }
  else if (i < 8388608L) { src = wf; dst = of; off = i - 4194304L; }
  else                   { src = wo; dst = oo; off = i - 8388608L; }
  float4 v0 = *(const float4*)(src + off);
  float4 v1 = *(const float4*)(src + off + 4);
  u16x8 o;
  o[0] = f2bf(v0.x); o[1] = f2bf(v0.y); o[2] = f2bf(v0.z); o[3] = f2bf(v0.w);
  o[4] = f2bf(v1.x); o[5] = f2bf(v1.y); o[6] = f2bf(v1.z); o[7] = f2bf(v1.w);
  *(u16x8*)(dst + off) = o;
}

__global__ __launch_bounds__(256) void conv_kernel(const float* __restrict__ in,
                                                   unsigned short* __restrict__ out, long n) {
  long i = (long)(blockIdx.x * 256 + threadIdx.x) * 8;
  if (i >= n) return;
  float4 v0 = *(const float4*)(in + i);
  float4 v1 = *(const float4*)(in + i + 4);
  u16x8 o;
  o[0] = f2bf(v0.x); o[1] = f2bf(v0.y); o[2] = f2bf(v0.z); o[3] = f2bf(v0.w);
  o[4] = f2bf(v1.x); o[5] = f2bf(v1.y); o[6] = f2bf(v1.z); o[7] = f2bf(v1.w);
  *(u16x8*)(out + i) = o;
}

// ---------------- layernorm: fp32 in -> bf16 out ----------------
__global__ __launch_bounds__(256) void layernorm_kernel(const float* __restrict__ x,
                                                        const float* __restrict__ g,
                                                        const float* __restrict__ b,
                                                        unsigned short* __restrict__ o) {
  int r = blockIdx.x;
  int tid = threadIdx.x;
  const float* row = x + (size_t)r * D_DIM;
  float4 v = *(const float4*)(row + tid * 4);
  float s  = v.x + v.y + v.z + v.w;
  float s2 = v.x * v.x + v.y * v.y + v.z * v.z + v.w * v.w;
  #pragma unroll
  for (int off = 32; off; off >>= 1) {
    s  += __shfl_xor(s, off);
    s2 += __shfl_xor(s2, off);
  }
  __shared__ float a1[4], a2[4];
  int w = tid >> 6, lane = tid & 63;
  if (lane == 0) { a1[w] = s; a2[w] = s2; }
  __syncthreads();
  s  = a1[0] + a1[1] + a1[2] + a1[3];
  s2 = a2[0] + a2[1] + a2[2] + a2[3];
  float mu  = s * (1.0f / D_DIM);
  float var = s2 * (1.0f / D_DIM) - mu * mu;
  float rs  = rsqrtf(var + LN_EPS);
  int d = tid * 4;
  float4 gv = *(const float4*)(g + d);
  float4 bv = *(const float4*)(b + d);
  ushort4 ov;
  ov.x = f2bf((v.x - mu) * rs * gv.x + bv.x);
  ov.y = f2bf((v.y - mu) * rs * gv.y + bv.y);
  ov.z = f2bf((v.z - mu) * rs * gv.z + bv.z);
  ov.w = f2bf((v.w - mu) * rs * gv.w + bv.w);
  *(ushort4*)(o + (size_t)r * D_DIM + d) = ov;
}

// ---------------- m97-structure 128x128 bf16 MFMA GEMM (proj/out) ----------
template<int EPI>
__global__ __launch_bounds__(256) void mfma_gemm(const unsigned short* __restrict__ A,
                                                 const unsigned short* __restrict__ W,
                                                 const float* R, void* Cout,
                                                 int K, int ldc, int nreal) {
  __shared__ unsigned short As[128 * 32];
  __shared__ unsigned short Bs[128 * 32];
  const int tid  = threadIdx.x;
  const int wave = tid >> 6, lane = tid & 63;
  const int wr = wave >> 1, wc = wave & 1;
  const long row0 = (long)blockIdx.y * 128;
  const long col0 = (long)blockIdx.x * 128;
  f32x4 acc[4][4] = {};
  const int frow = lane & 15;
  const int fk   = (lane >> 4) * 8;
  const int b0 = wave * 2048 + lane * 16;
  for (int k0 = 0; k0 < K; k0 += 32) {
    #pragma unroll
    for (int c = 0; c < 2; ++c) {
      int b = b0 + c * 1024;
      int r = b >> 6, ke = (b & 63) >> 1;
      gload_lds16(A + (row0 + r) * (long)K + k0 + ke, (char*)As + b);
      gload_lds16(W + (col0 + r) * (long)K + k0 + ke, (char*)Bs + b);
    }
    __syncthreads();
    bf16x8 af[4], bfr[4];
    #pragma unroll
    for (int i = 0; i < 4; ++i)
      af[i] = *(const bf16x8*)(As + (wr * 64 + i * 16 + frow) * 32 + fk);
    #pragma unroll
    for (int j = 0; j < 4; ++j)
      bfr[j] = *(const bf16x8*)(Bs + (wc * 64 + j * 16 + frow) * 32 + fk);
    #pragma unroll
    for (int i = 0; i < 4; ++i)
      #pragma unroll
      for (int j = 0; j < 4; ++j)
        acc[i][j] = __builtin_amdgcn_mfma_f32_16x16x32_bf16(af[i], bfr[j], acc[i][j], 0, 0, 0);
    __syncthreads();
  }
  const int crow = (lane >> 4) * 4;
  const int ccol = lane & 15;
  #pragma unroll
  for (int i = 0; i < 4; ++i) {
    #pragma unroll
    for (int r = 0; r < 4; ++r) {
      long row = row0 + wr * 64 + i * 16 + crow + r;
      #pragma unroll
      for (int j = 0; j < 4; ++j) {
        long col = col0 + wc * 64 + j * 16 + ccol;
        float v = acc[i][j][r];
        if (EPI == 1) {
          ((float*)Cout)[row * (long)ldc + col] = v + R[row * (long)ldc + col];
        } else {
          ((float*)Cout)[row * (long)ldc + col] = v;
        }
      }
    }
  }
}

// ---------------- 256x256 8-phase counted-vmcnt bf16 GEMM (qkv/fc/logits) ----------
// Identical to Round-4 version EXCEPT the end-of-iteration wait: the last two
// iterations drain vmcnt(0) (tail fix — tile nt-1's kk1 chunks were still in
// flight when iteration nt-1 read them; no stages are issued after t=nt-3's
// phase 3, so vmcnt(4) waited for nothing).
__device__ __forceinline__ void stage_chunk8(const unsigned short* __restrict__ base,
                                             long rbase, int K, long gk,
                                             char* cb, int tid) {
  #pragma unroll
  for (int j = 0; j < 2; ++j) {
    int db = j * 8192 + tid * 16;
    int lb = db ^ (((db >> 7) & 3) << 4);
    long r = lb >> 6;
    int e = (lb & 63) >> 1;
    gload_lds16(base + (rbase + r) * (long)K + gk + e, cb + db);
  }
}

__device__ __forceinline__ bf16x8 rdfrag(const char* cb, int rr, int lhi) {
  int p = (rr << 6) + (lhi << 4);
  p ^= ((rr >> 1) & 3) << 4;
  return *(const bf16x8*)(cb + p);
}

template<int EPI>
__global__ __launch_bounds__(512, 1) void gemm8p(const unsigned short* __restrict__ A,
                                                 const unsigned short* __restrict__ W,
                                                 void* Cout, int K, int ldc, int nreal,
                                                 int nbx, int xcd) {
  __shared__ char lds[131072];
  const int tid  = threadIdx.x;
  const int lane = tid & 63;
  const int wave = tid >> 6;
  const int wr = wave >> 2, wc = wave & 3;
  const int lhi = lane >> 4, llo = lane & 15;
  int bid = blockIdx.x;
  if (xcd) { int per = (int)gridDim.x >> 3; bid = (bid & 7) * per + (bid >> 3); }
  const int brow = bid % nbx;
  const int bcol = bid / nbx;
  const long row0 = (long)brow * 256;
  const long col0 = (long)bcol * 256;
  char* Ab0 = (char*)lds;
  char* Bb0 = (char*)lds + 65536;
  const int nt = K >> 6;

  stage_chunk8(A, row0, K, 0,  Ab0,         tid);
  stage_chunk8(W, col0, K, 0,  Bb0,         tid);
  stage_chunk8(A, row0, K, 32, Ab0 + 16384, tid);
  stage_chunk8(W, col0, K, 32, Bb0 + 16384, tid);
  if (nt > 1) {
    stage_chunk8(A, row0, K, 64, Ab0 + 32768, tid);
    stage_chunk8(W, col0, K, 64, Bb0 + 32768, tid);
    asm volatile("s_waitcnt vmcnt(4)" ::: "memory");
  } else {
    asm volatile("s_waitcnt vmcnt(0)" ::: "memory");
  }
  BARSB();

  f32x4 acc[8][4] = {};
  bf16x8 bb[4];
  for (int t = 0; t < nt; ++t) {
    char* Ac = Ab0 + (t & 1) * 32768;
    char* Bc = Bb0 + (t & 1) * 32768;
    char* An = Ab0 + ((t + 1) & 1) * 32768;
    char* Bn = Bb0 + ((t + 1) & 1) * 32768;
    bf16x8 aa[4];
    // ---- phase 0: A m0-3 kk0 + B kk0; stage A-k1(t+1) ----
    #pragma unroll
    for (int m = 0; m < 4; ++m) aa[m] = rdfrag(Ac, wr * 128 + m * 16 + llo, lhi);
    #pragma unroll
    for (int n = 0; n < 4; ++n) bb[n] = rdfrag(Bc, wc * 64 + n * 16 + llo, lhi);
    if (t + 1 < nt) stage_chunk8(A, row0, K, (long)(t + 1) * 64 + 32, An + 16384, tid);
    BARSB(); LGKM0();
    __builtin_amdgcn_s_setprio(1);
    #pragma unroll
    for (int m = 0; m < 4; ++m)
      #pragma unroll
      for (int n = 0; n < 4; ++n)
        acc[m][n] = __builtin_amdgcn_mfma_f32_16x16x32_bf16(aa[m], bb[n], acc[m][n], 0, 0, 0);
    __builtin_amdgcn_s_setprio(0);
    BARSB();
    // ---- phase 1: A m4-7 kk0 (B kk0 reused); stage B-k1(t+1) ----
    #pragma unroll
    for (int m = 0; m < 4; ++m) aa[m] = rdfrag(Ac, wr * 128 + 64 + m * 16 + llo, lhi);
    if (t + 1 < nt) stage_chunk8(W, col0, K, (long)(t + 1) * 64 + 32, Bn + 16384, tid);
    BARSB(); LGKM0();
    __builtin_amdgcn_s_setprio(1);
    #pragma unroll
    for (int m = 0; m < 4; ++m)
      #pragma unroll
      for (int n = 0; n < 4; ++n)
        acc[m + 4][n] = __builtin_amdgcn_mfma_f32_16x16x32_bf16(aa[m], bb[n], acc[m + 4][n], 0, 0, 0);
    __builtin_amdgcn_s_setprio(0);
    BARSB();
    // ---- phase 2: A m0-3 kk1 + B kk1; stage A-k0(t+2) into Ac ----
    #pragma unroll
    for (int m = 0; m < 4; ++m) aa[m] = rdfrag(Ac + 16384, wr * 128 + m * 16 + llo, lhi);
    #pragma unroll
    for (int n = 0; n < 4; ++n) bb[n] = rdfrag(Bc + 16384, wc * 64 + n * 16 + llo, lhi);
    if (t + 2 < nt) stage_chunk8(A, row0, K, (long)(t + 2) * 64, Ac, tid);
    BARSB(); LGKM0();
    __builtin_amdgcn_s_setprio(1);
    #pragma unroll
    for (int m = 0; m < 4; ++m)
      #pragma unroll
      for (int n = 0; n < 4; ++n)
        acc[m][n] = __builtin_amdgcn_mfma_f32_16x16x32_bf16(aa[m], bb[n], acc[m][n], 0, 0, 0);
    __builtin_amdgcn_s_setprio(0);
    BARSB();
    // ---- phase 3: A m4-7 kk1; stage B-k0(t+2) into Bc; counted drain ----
    #pragma unroll
    for (int m = 0; m < 4; ++m) aa[m] = rdfrag(Ac + 16384, wr * 128 + 64 + m * 16 + llo, lhi);
    if (t + 2 < nt) stage_chunk8(W, col0, K, (long)(t + 2) * 64, Bc, tid);
    BARSB(); LGKM0();
    __builtin_amdgcn_s_setprio(1);
    #pragma unroll
    for (int m = 0; m < 4; ++m)
      #pragma unroll
      for (int n = 0; n < 4; ++n)
        acc[m + 4][n] = __builtin_amdgcn_mfma_f32_16x16x32_bf16(aa[m], bb[n], acc[m + 4][n], 0, 0, 0);
    __builtin_amdgcn_s_setprio(0);
    if (t < nt - 2) {
      asm volatile("s_waitcnt vmcnt(4)" ::: "memory");
    } else {
      asm volatile("s_waitcnt vmcnt(0)" ::: "memory");   // tail fix: drain kk1 of last tile
    }
    BARSB();
  }

  #pragma unroll
  for (int mi = 0; mi < 8; ++mi) {
    #pragma unroll
    for (int rg = 0; rg < 4; ++rg) {
      long row = row0 + wr * 128 + mi * 16 + lhi * 4 + rg;
      #pragma unroll
      for (int n = 0; n < 4; ++n) {
        long col = col0 + wc * 64 + n * 16 + llo;
        float v = acc[mi][n][rg];
        if (EPI == 0) {
          if (col < nreal) ((float*)Cout)[row * (long)ldc + col] = v;
        } else if (EPI == 2) {
          float gl = 0.5f * v * (1.0f + erff(v * 0.70710678118654752440f));
          ((unsigned short*)Cout)[row * (long)ldc + col] = f2bf(gl);
        } else {
          ((unsigned short*)Cout)[row * (long)ldc + col] = f2bf(v);
        }
      }
    }
  }
}

// ---------------- MFMA flash attention ----------------
__global__ __launch_bounds__(256) void flash_attn_kernel(const unsigned short* __restrict__ qkv,
                                                         unsigned short* __restrict__ y) {
  __shared__ unsigned short Kls[64 * 64];
  __shared__ unsigned short Vtls[64 * 64];
  __shared__ unsigned short Pls[4][16 * 64];
  const int tid = threadIdx.x, wave = tid >> 6, lane = tid & 63;
  const int qt = blockIdx.x;
  const int h = blockIdx.y & (H_NUM - 1), b = blockIdx.y >> 4;
  const int q0 = qt * 64;
  const int lhi = lane >> 4, llo = lane & 15;

  const int qrow = q0 + wave * 16 + llo;
  const unsigned short* qptr =
      qkv + ((size_t)(b * T_LEN + qrow)) * 3072 + h * HD_DIM + lhi * 8;
  const bf16x8 qa0 = *(const bf16x8*)qptr;
  const bf16x8 qa1 = *(const bf16x8*)(qptr + 32);

  f32x4 o[4] = {};
  float m[4] = {-1e30f, -1e30f, -1e30f, -1e30f};
  float l[4] = {0.f, 0.f, 0.f, 0.f};

  const unsigned short* kg = qkv + (size_t)b * T_LEN * 3072 + D_DIM + h * HD_DIM;
  const unsigned short* vg = kg + D_DIM;

  const int krow = tid >> 2, kcol = (tid & 3) * 16;
  const int vs0 = (tid >> 3) * 2, vd0 = (tid & 7) * 8;

  const int ntiles = qt + 1;
  for (int st = 0; st < ntiles; ++st) {
    const int s0 = st * 64;
    {
      const unsigned short* src = kg + (size_t)(s0 + krow) * 3072 + kcol;
      u16x8 a = *(const u16x8*)src;
      u16x8 c = *(const u16x8*)(src + 8);
      int base = krow * 128 + kcol * 2;
      int sw = (krow & 7) << 4;
      *(u16x8*)((char*)Kls + ((base) ^ sw))      = a;
      *(u16x8*)((char*)Kls + ((base + 16) ^ sw)) = c;
    }
    {
      const unsigned short* src = vg + (size_t)(s0 + vs0) * 3072 + vd0;
      u16x8 a = *(const u16x8*)src;
      u16x8 c = *(const u16x8*)(src + 3072);
      #pragma unroll
      for (int j = 0; j < 8; ++j) {
        int d = vd0 + j;
        unsigned val = (unsigned)a[j] | ((unsigned)c[j] << 16);
        *(unsigned*)((char*)Vtls + ((d * 128 + vs0 * 2) ^ ((d & 7) << 4))) = val;
      }
    }
    __syncthreads();

    f32x4 s_acc[4] = {};
    #pragma unroll
    for (int kt = 0; kt < 4; ++kt) {
      int kr = kt * 16 + llo;
      int sw = (kr & 7) << 4;
      bf16x8 kb0 = *(const bf16x8*)((char*)Kls + ((kr * 128 + lhi * 16) ^ sw));
      bf16x8 kb1 = *(const bf16x8*)((char*)Kls + ((kr * 128 + 64 + lhi * 16) ^ sw));
      s_acc[kt] = __builtin_amdgcn_mfma_f32_16x16x32_bf16(qa0, kb0, s_acc[kt], 0, 0, 0);
      s_acc[kt] = __builtin_amdgcn_mfma_f32_16x16x32_bf16(qa1, kb1, s_acc[kt], 0, 0, 0);
    }

    float p[4][4];
    float tmax[4] = {-1e30f, -1e30f, -1e30f, -1e30f};
    const int qg = q0 + wave * 16 + lhi * 4;
    #pragma unroll
    for (int kt = 0; kt < 4; ++kt) {
      int ks = s0 + kt * 16 + llo;
      #pragma unroll
      for (int r = 0; r < 4; ++r) {
        float sv = (ks <= qg + r) ? s_acc[kt][r] * 0.125f : -1e30f;
        p[kt][r] = sv;
        tmax[r] = fmaxf(tmax[r], sv);
      }
    }
    #pragma unroll
    for (int r = 0; r < 4; ++r) {
      #pragma unroll
      for (int off = 1; off < 16; off <<= 1)
        tmax[r] = fmaxf(tmax[r], __shfl_xor(tmax[r], off));
      float mn = fmaxf(m[r], tmax[r]);
      float corr = __expf(m[r] - mn);
      m[r] = mn;
      float ps = 0.f;
      #pragma unroll
      for (int kt = 0; kt < 4; ++kt) {
        p[kt][r] = __expf(p[kt][r] - mn);
        ps += p[kt][r];
      }
      #pragma unroll
      for (int off = 1; off < 16; off <<= 1)
        ps += __shfl_xor(ps, off);
      l[r] = l[r] * corr + ps;
      #pragma unroll
      for (int dt = 0; dt < 4; ++dt) o[dt][r] *= corr;
    }

    unsigned short* pw = Pls[wave];
    #pragma unroll
    for (int r = 0; r < 4; ++r) {
      int q = lhi * 4 + r;
      int sw = (q & 7) << 4;
      #pragma unroll
      for (int kt = 0; kt < 4; ++kt) {
        int k = kt * 16 + llo;
        *(unsigned short*)((char*)pw + ((q * 128 + k * 2) ^ sw)) = f2bf(p[kt][r]);
      }
    }
    asm volatile("s_waitcnt lgkmcnt(0)" ::: "memory");

    int psw = (llo & 7) << 4;
    bf16x8 pa0 = *(const bf16x8*)((char*)pw + ((llo * 128 + lhi * 16) ^ psw));
    bf16x8 pa1 = *(const bf16x8*)((char*)pw + ((llo * 128 + 64 + lhi * 16) ^ psw));
    #pragma unroll
    for (int dt = 0; dt < 4; ++dt) {
      int vr = dt * 16 + llo;
      int sw = (vr & 7) << 4;
      bf16x8 vb0 = *(const bf16x8*)((char*)Vtls + ((vr * 128 + lhi * 16) ^ sw));
      bf16x8 vb1 = *(const bf16x8*)((char*)Vtls + ((vr * 128 + 64 + lhi * 16) ^ sw));
      o[dt] = __builtin_amdgcn_mfma_f32_16x16x32_bf16(pa0, vb0, o[dt], 0, 0, 0);
      o[dt] = __builtin_amdgcn_mfma_f32_16x16x32_bf16(pa1, vb1, o[dt], 0, 0, 0);
    }
    __syncthreads();
  }

  #pragma unroll
  for (int r = 0; r < 4; ++r) {
    long row = q0 + wave * 16 + lhi * 4 + r;
    float inv = 1.0f / l[r];
    #pragma unroll
    for (int dt = 0; dt < 4; ++dt) {
      long col = h * HD_DIM + dt * 16 + llo;
      y[(row + (size_t)b * T_LEN) * D_DIM + col] = f2bf(o[dt][r] * inv);
    }
  }
}

// ---------------- loss ----------------
__global__ __launch_bounds__(256) void loss_rows_kernel(const float* __restrict__ logits,
                                                        const int* __restrict__ tgt,
                                                        float* __restrict__ nll,
                                                        float* __restrict__ vld) {
  int r = blockIdx.x;
  int tid = threadIdx.x;
  const float* row = logits + (size_t)r * V_SIZE;
  float mx = -1e30f;
  for (int i = tid; i < V_SIZE; i += 256) mx = fmaxf(mx, row[i]);
  #pragma unroll
  for (int off = 32; off; off >>= 1) mx = fmaxf(mx, __shfl_xor(mx, off));
  __shared__ float sm[4], ss[4];
  int w = tid >> 6, lane = tid & 63;
  if (lane == 0) sm[w] = mx;
  __syncthreads();
  mx = fmaxf(fmaxf(sm[0], sm[1]), fmaxf(sm[2], sm[3]));
  float se = 0.f;
  for (int i = tid; i < V_SIZE; i += 256) se += expf(row[i] - mx);
  #pragma unroll
  for (int off = 32; off; off >>= 1) se += __shfl_xor(se, off);
  if (lane == 0) ss[w] = se;
  __syncthreads();
  if (tid == 0) {
    se = ss[0] + ss[1] + ss[2] + ss[3];
    int tg = tgt[r];
    if (tg != -1) { nll[r] = mx + logf(se) - row[tg]; vld[r] = 1.0f; }
    else          { nll[r] = 0.f;                     vld[r] = 0.f; }
  }
}

__global__ __launch_bounds__(256) void loss_reduce_kernel(const float* __restrict__ nll,
                                                          const float* __restrict__ vld,
                                                          float* __restrict__ out) {
  int tid = threadIdx.x;
  float s = 0.f, c = 0.f;
  for (int i = tid; i < M_ROWS; i += 256) { s += nll[i]; c += vld[i]; }
  #pragma unroll
  for (int off = 32; off; off >>= 1) { s += __shfl_xor(s, off); c += __shfl_xor(c, off); }
  __shared__ float s1[4], s2[4];
  int w = tid >> 6, lane = tid & 63;
  if (lane == 0) { s1[w] = s; s2[w] = c; }
  __syncthreads();
  if (tid == 0) {
    s = s1[0] + s1[1] + s1[2] + s1[3];
    c = s2[0] + s2[1] + s2[2] + s2[3];
    out[0] = s / fmaxf(c, 1.0f);
  }
}

extern "C" void kernel_launch(void* const* d_in, const int* in_sizes, int n_in,
                              void* d_out, int out_size, void* d_ws, size_t ws_size,
                              hipStream_t stream) {
  const int*   ctx    = (const int*)d_in[0];
  const int*   tgt    = (const int*)d_in[1];
  const float* wte    = (const float*)d_in[2];
  const float* wpe    = (const float*)d_in[3];
  const float* ln1_g  = (const float*)d_in[4];
  const float* ln1_b  = (const float*)d_in[5];
  const float* w_attn = (const float*)d_in[6];
  const float* w_proj = (const float*)d_in[7];
  const float* ln2_g  = (const float*)d_in[8];
  const float* ln2_b  = (const float*)d_in[9];
  const float* w_fc   = (const float*)d_in[10];
  const float* w_out  = (const float*)d_in[11];
  const float* lnf_g  = (const float*)d_in[12];
  const float* lnf_b  = (const float*)d_in[13];

  float* outp   = (float*)d_out;
  float* logits = outp;
  float* loss   = outp + (size_t)M_ROWS * V_SIZE;

  // ---- workspace layout (bytes), max ~128.5 MB ----
  char* ws = (char*)d_ws;
  float*          x      = (float*)(ws + 0);                    // fp32 [4096][1024]
  unsigned short* xn     = (unsigned short*)(ws + 16777216);    // bf16 [4096][1024]
  unsigned short* qkv    = (unsigned short*)(ws + 25165824);    // bf16 [4096][3072]
  unsigned short* y      = (unsigned short*)(ws + 50331648);    // bf16 [4096][1024]
  unsigned short* h      = (unsigned short*)(ws + 58720256);    // bf16 [4096][4096]
  unsigned short* wa_bf  = (unsigned short*)(ws + 92274688);
  unsigned short* wp_bf  = (unsigned short*)(ws + 98566144);
  unsigned short* wf_bf  = (unsigned short*)(ws + 100663296);
  unsigned short* wo_bf  = (unsigned short*)(ws + 109051904);
  unsigned short* wte_bf = (unsigned short*)(ws + 25165824);    // alias post-loop [50432][1024]
  float*          nll    = (float*)(ws + 128450560);
  float*          vld    = (float*)(ws + 128466944);

  embed_kernel<<<(M_ROWS * D_DIM + 255) / 256, 256, 0, stream>>>(ctx, wte, wpe, x);

  for (int l = 0; l < L_NUM; ++l) {
    conv_layer_kernel<<<6144, 256, 0, stream>>>(
        w_attn + (size_t)l * 3 * D_DIM * D_DIM, w_proj + (size_t)l * D_DIM * D_DIM,
        w_fc + (size_t)l * 4 * D_DIM * D_DIM, w_out + (size_t)l * D_DIM * 4 * D_DIM,
        wa_bf, wp_bf, wf_bf, wo_bf);
    layernorm_kernel<<<M_ROWS, 256, 0, stream>>>(x, ln1_g + l * D_DIM, ln1_b + l * D_DIM, xn);
    gemm8p<3><<<12 * 16, 512, 0, stream>>>(
        xn, wa_bf, qkv, D_DIM, 3 * D_DIM, 3 * D_DIM, 16, 0);
    flash_attn_kernel<<<dim3(T_LEN / 64, B_NUM * H_NUM), 256, 0, stream>>>(qkv, y);
    mfma_gemm<1><<<dim3(D_DIM / 128, M_ROWS / 128), 256, 0, stream>>>(
        y, wp_bf, x, x, D_DIM, D_DIM, D_DIM);
    layernorm_kernel<<<M_ROWS, 256, 0, stream>>>(x, ln2_g + l * D_DIM, ln2_b + l * D_DIM, xn);
    gemm8p<2><<<16 * 16, 512, 0, stream>>>(
        xn, wf_bf, h, D_DIM, 4 * D_DIM, 4 * D_DIM, 16, 0);
    mfma_gemm<1><<<dim3(D_DIM / 128, M_ROWS / 128), 256, 0, stream>>>(
        h, wo_bf, x, x, 4 * D_DIM, D_DIM, D_DIM);
  }

  layernorm_kernel<<<M_ROWS, 256, 0, stream>>>(x, lnf_g, lnf_b, xn);
  conv_kernel<<<25129, 256, 0, stream>>>(wte, wte_bf, (long)V_SIZE * D_DIM);
  hipMemsetAsync(wte_bf + (size_t)V_SIZE * D_DIM, 0,
                 (size_t)(V_PAD - V_SIZE) * D_DIM * sizeof(unsigned short), stream);
  gemm8p<0><<<197 * 16, 512, 0, stream>>>(
      xn, wte_bf, logits, D_DIM, V_SIZE, V_SIZE, 16, 1);
  loss_rows_kernel<<<M_ROWS, 256, 0, stream>>>(logits, tgt, nll, vld);
  loss_reduce_kernel<<<1, 256, 0, stream>>>(nll, vld, loss);
}

// Round 6
// 3489.735 us; speedup vs baseline: 13.0462x; 1.0476x over previous
//
#include <hip/hip_runtime.h>
#include <cstdint>

#define V_SIZE 50257
#define V_PAD  50432            // 197 * 256
#define D_DIM  1024
#define H_NUM  16
#define L_NUM  8
#define T_LEN  1024
#define B_NUM  4
#define HD_DIM 64
#define M_ROWS 4096
#define LN_EPS 1e-5f

typedef __attribute__((ext_vector_type(8))) __bf16 bf16x8;
typedef __attribute__((ext_vector_type(4))) float f32x4;
typedef __attribute__((ext_vector_type(8))) unsigned short u16x8;

__device__ __forceinline__ unsigned short f2bf(float f) {
  unsigned u = __builtin_bit_cast(unsigned, f);
  u += 0x7fffu + ((u >> 16) & 1u);   // RNE
  return (unsigned short)(u >> 16);
}

__device__ __forceinline__ void gload_lds16(const void* g, void* l) {
  typedef const __attribute__((address_space(1))) unsigned int* gp_t;
  typedef __attribute__((address_space(3))) unsigned int* lp_t;
  __builtin_amdgcn_global_load_lds((gp_t)g, (lp_t)l, 16, 0, 0);
}

#define BARSB() { __builtin_amdgcn_s_barrier(); __builtin_amdgcn_sched_barrier(0); }
#define LGKM0() { asm volatile("s_waitcnt lgkmcnt(0)" ::: "memory"); __builtin_amdgcn_sched_barrier(0); }

// ---------------- embedding ----------------
__global__ __launch_bounds__(256) void embed_kernel(const int* __restrict__ ctx,
                                                    const float* __restrict__ wte,
                                                    const float* __restrict__ wpe,
                                                    float* __restrict__ x) {
  int i = blockIdx.x * blockDim.x + threadIdx.x;
  if (i >= M_ROWS * D_DIM) return;
  int bt = i / D_DIM, d = i - bt * D_DIM;
  int t = bt & (T_LEN - 1);
  x[i] = wte[(size_t)ctx[bt] * D_DIM + d] + wpe[(size_t)t * D_DIM + d];
}

// ---------------- fp32 -> bf16 weight conversion ----------------
__global__ __launch_bounds__(256) void conv_layer_kernel(const float* __restrict__ wa,
                                                         const float* __restrict__ wp,
                                                         const float* __restrict__ wf,
                                                         const float* __restrict__ wo,
                                                         unsigned short* __restrict__ oa,
                                                         unsigned short* __restrict__ op,
                                                         unsigned short* __restrict__ of,
                                                         unsigned short* __restrict__ oo) {
  long i = (long)(blockIdx.x * 256 + threadIdx.x) * 8;
  const float* src; unsigned short* dst; long off;
  if (i < 3145728L)      { src = wa; dst = oa; off = i; }
  else if (i < 4194304L) { src = wp; dst = op; off = i - 3145728L; }
  else if (i < 8388608L) { src = wf; dst = of; off = i - 4194304L; }
  else                   { src = wo; dst = oo; off = i - 8388608L; }
  float4 v0 = *(const float4*)(src + off);
  float4 v1 = *(const float4*)(src + off + 4);
  u16x8 o;
  o[0] = f2bf(v0.x); o[1] = f2bf(v0.y); o[2] = f2bf(v0.z); o[3] = f2bf(v0.w);
  o[4] = f2bf(v1.x); o[5] = f2bf(v1.y); o[6] = f2bf(v1.z); o[7] = f2bf(v1.w);
  *(u16x8*)(dst + off) = o;
}

__global__ __launch_bounds__(256) void conv_kernel(const float* __restrict__ in,
                                                   unsigned short* __restrict__ out, long n) {
  long i = (long)(blockIdx.x * 256 + threadIdx.x) * 8;
  if (i >= n) return;
  float4 v0 = *(const float4*)(in + i);
  float4 v1 = *(const float4*)(in + i + 4);
  u16x8 o;
  o[0] = f2bf(v0.x); o[1] = f2bf(v0.y); o[2] = f2bf(v0.z); o[3] = f2bf(v0.w);
  o[4] = f2bf(v1.x); o[5] = f2bf(v1.y); o[6] = f2bf(v1.z); o[7] = f2bf(v1.w);
  *(u16x8*)(out + i) = o;
}

// ---------------- layernorm: fp32 in -> bf16 out ----------------
__global__ __launch_bounds__(256) void layernorm_kernel(const float* __restrict__ x,
                                                        const float* __restrict__ g,
                                                        const float* __restrict__ b,
                                                        unsigned short* __restrict__ o) {
  int r = blockIdx.x;
  int tid = threadIdx.x;
  const float* row = x + (size_t)r * D_DIM;
  float4 v = *(const float4*)(row + tid * 4);
  float s  = v.x + v.y + v.z + v.w;
  float s2 = v.x * v.x + v.y * v.y + v.z * v.z + v.w * v.w;
  #pragma unroll
  for (int off = 32; off; off >>= 1) {
    s  += __shfl_xor(s, off);
    s2 += __shfl_xor(s2, off);
  }
  __shared__ float a1[4], a2[4];
  int w = tid >> 6, lane = tid & 63;
  if (lane == 0) { a1[w] = s; a2[w] = s2; }
  __syncthreads();
  s  = a1[0] + a1[1] + a1[2] + a1[3];
  s2 = a2[0] + a2[1] + a2[2] + a2[3];
  float mu  = s * (1.0f / D_DIM);
  float var = s2 * (1.0f / D_DIM) - mu * mu;
  float rs  = rsqrtf(var + LN_EPS);
  int d = tid * 4;
  float4 gv = *(const float4*)(g + d);
  float4 bv = *(const float4*)(b + d);
  ushort4 ov;
  ov.x = f2bf((v.x - mu) * rs * gv.x + bv.x);
  ov.y = f2bf((v.y - mu) * rs * gv.y + bv.y);
  ov.z = f2bf((v.z - mu) * rs * gv.z + bv.z);
  ov.w = f2bf((v.w - mu) * rs * gv.w + bv.w);
  *(ushort4*)(o + (size_t)r * D_DIM + d) = ov;
}

// ---------------- m97-structure 128x128 bf16 MFMA GEMM (proj/out) ----------
template<int EPI>
__global__ __launch_bounds__(256) void mfma_gemm(const unsigned short* __restrict__ A,
                                                 const unsigned short* __restrict__ W,
                                                 const float* R, void* Cout,
                                                 int K, int ldc, int nreal) {
  __shared__ unsigned short As[128 * 32];
  __shared__ unsigned short Bs[128 * 32];
  const int tid  = threadIdx.x;
  const int wave = tid >> 6, lane = tid & 63;
  const int wr = wave >> 1, wc = wave & 1;
  const long row0 = (long)blockIdx.y * 128;
  const long col0 = (long)blockIdx.x * 128;
  f32x4 acc[4][4] = {};
  const int frow = lane & 15;
  const int fk   = (lane >> 4) * 8;
  const int b0 = wave * 2048 + lane * 16;
  for (int k0 = 0; k0 < K; k0 += 32) {
    #pragma unroll
    for (int c = 0; c < 2; ++c) {
      int b = b0 + c * 1024;
      int r = b >> 6, ke = (b & 63) >> 1;
      gload_lds16(A + (row0 + r) * (long)K + k0 + ke, (char*)As + b);
      gload_lds16(W + (col0 + r) * (long)K + k0 + ke, (char*)Bs + b);
    }
    __syncthreads();
    bf16x8 af[4], bfr[4];
    #pragma unroll
    for (int i = 0; i < 4; ++i)
      af[i] = *(const bf16x8*)(As + (wr * 64 + i * 16 + frow) * 32 + fk);
    #pragma unroll
    for (int j = 0; j < 4; ++j)
      bfr[j] = *(const bf16x8*)(Bs + (wc * 64 + j * 16 + frow) * 32 + fk);
    #pragma unroll
    for (int i = 0; i < 4; ++i)
      #pragma unroll
      for (int j = 0; j < 4; ++j)
        acc[i][j] = __builtin_amdgcn_mfma_f32_16x16x32_bf16(af[i], bfr[j], acc[i][j], 0, 0, 0);
    __syncthreads();
  }
  const int crow = (lane >> 4) * 4;
  const int ccol = lane & 15;
  #pragma unroll
  for (int i = 0; i < 4; ++i) {
    #pragma unroll
    for (int r = 0; r < 4; ++r) {
      long row = row0 + wr * 64 + i * 16 + crow + r;
      #pragma unroll
      for (int j = 0; j < 4; ++j) {
        long col = col0 + wc * 64 + j * 16 + ccol;
        float v = acc[i][j][r];
        if (EPI == 1) {
          ((float*)Cout)[row * (long)ldc + col] = v + R[row * (long)ldc + col];
        } else {
          ((float*)Cout)[row * (long)ldc + col] = v;
        }
      }
    }
  }
}

// ---------------- 256x256 8-phase counted-vmcnt bf16 GEMM (qkv/fc/logits) ----------
// Max-depth dbuf staging: each LDS region restaged right after its last reader
// phase. Iter t: ph0->A-kk1(t+1), ph1->B-kk0(t+2), ph2->A-kk0(t+2),
// ph3->B-kk1(t+2). Two counted waits/iter: W_a after ph1 (vmcnt 10/8/0),
// W_b after ph3 (vmcnt 10/4/0) -- min issue->wait lead = 5 phases (vs 2-3 in
// the round-5 schedule, which was the MfmaUtil=29% stall).
__device__ __forceinline__ void stage_chunk8(const unsigned short* __restrict__ base,
                                             long rbase, int K, long gk,
                                             char* cb, int tid) {
  #pragma unroll
  for (int j = 0; j < 2; ++j) {
    int db = j * 8192 + tid * 16;
    int lb = db ^ (((db >> 7) & 3) << 4);
    long r = lb >> 6;
    int e = (lb & 63) >> 1;
    gload_lds16(base + (rbase + r) * (long)K + gk + e, cb + db);
  }
}

__device__ __forceinline__ bf16x8 rdfrag(const char* cb, int rr, int lhi) {
  int p = (rr << 6) + (lhi << 4);
  p ^= ((rr >> 1) & 3) << 4;
  return *(const bf16x8*)(cb + p);
}

template<int EPI>
__global__ __launch_bounds__(512, 1) void gemm8p(const unsigned short* __restrict__ A,
                                                 const unsigned short* __restrict__ W,
                                                 void* Cout, int K, int ldc, int nreal,
                                                 int nbx, int xcd) {
  __shared__ char lds[131072];
  const int tid  = threadIdx.x;
  const int lane = tid & 63;
  const int wave = tid >> 6;
  const int wr = wave >> 2, wc = wave & 3;
  const int lhi = lane >> 4, llo = lane & 15;
  int bid = blockIdx.x;
  if (xcd) { int per = (int)gridDim.x >> 3; bid = (bid & 7) * per + (bid >> 3); }
  const int brow = bid % nbx;
  const int bcol = bid / nbx;
  const long row0 = (long)brow * 256;
  const long col0 = (long)bcol * 256;
  char* Ab0 = (char*)lds;
  char* Bb0 = (char*)lds + 65536;
  const int nt = K >> 6;

  // prologue: A0(0),B0(0),A1(0),B1(0),B0(1),A0(1),B1(1)  (A1(1) staged by ph0 of t=0)
  stage_chunk8(A, row0, K, 0,  Ab0,         tid);
  stage_chunk8(W, col0, K, 0,  Bb0,         tid);
  stage_chunk8(A, row0, K, 32, Ab0 + 16384, tid);
  stage_chunk8(W, col0, K, 32, Bb0 + 16384, tid);
  if (nt > 1) {
    stage_chunk8(W, col0, K, 64, Bb0 + 32768, tid);
    stage_chunk8(A, row0, K, 64, Ab0 + 32768, tid);
    stage_chunk8(W, col0, K, 96, Bb0 + 49152, tid);
    asm volatile("s_waitcnt vmcnt(10)" ::: "memory");
  } else {
    asm volatile("s_waitcnt vmcnt(0)" ::: "memory");
  }
  BARSB();

  f32x4 acc[8][4] = {};
  bf16x8 bb[4];
  for (int t = 0; t < nt; ++t) {
    char* Ac = Ab0 + (t & 1) * 32768;
    char* Bc = Bb0 + (t & 1) * 32768;
    char* An = Ab0 + ((t + 1) & 1) * 32768;
    bf16x8 aa[4];
    // ---- phase 0: read A m0-3 kk0 + B kk0; stage A-kk1(t+1) ----
    #pragma unroll
    for (int m = 0; m < 4; ++m) aa[m] = rdfrag(Ac, wr * 128 + m * 16 + llo, lhi);
    #pragma unroll
    for (int n = 0; n < 4; ++n) bb[n] = rdfrag(Bc, wc * 64 + n * 16 + llo, lhi);
    if (t + 1 < nt) stage_chunk8(A, row0, K, (long)(t + 1) * 64 + 32, An + 16384, tid);
    BARSB(); LGKM0();
    __builtin_amdgcn_s_setprio(1);
    #pragma unroll
    for (int m = 0; m < 4; ++m)
      #pragma unroll
      for (int n = 0; n < 4; ++n)
        acc[m][n] = __builtin_amdgcn_mfma_f32_16x16x32_bf16(aa[m], bb[n], acc[m][n], 0, 0, 0);
    __builtin_amdgcn_s_setprio(0);
    BARSB();
    // ---- phase 1: read A m4-7 kk0; stage B-kk0(t+2) into Bc ----
    #pragma unroll
    for (int m = 0; m < 4; ++m) aa[m] = rdfrag(Ac, wr * 128 + 64 + m * 16 + llo, lhi);
    if (t + 2 < nt) stage_chunk8(W, col0, K, (long)(t + 2) * 64, Bc, tid);
    BARSB(); LGKM0();
    __builtin_amdgcn_s_setprio(1);
    #pragma unroll
    for (int m = 0; m < 4; ++m)
      #pragma unroll
      for (int n = 0; n < 4; ++n)
        acc[m + 4][n] = __builtin_amdgcn_mfma_f32_16x16x32_bf16(aa[m], bb[n], acc[m + 4][n], 0, 0, 0);
    __builtin_amdgcn_s_setprio(0);
    // W_a: covers kk1(t) (A1 issued ph0(t-1), B1 issued ph3(t-2): >=5 phases lead)
    if (t <= nt - 3)      { asm volatile("s_waitcnt vmcnt(10)" ::: "memory"); }
    else if (t == nt - 2) { asm volatile("s_waitcnt vmcnt(8)"  ::: "memory"); }
    else                  { asm volatile("s_waitcnt vmcnt(0)"  ::: "memory"); }
    BARSB();
    // ---- phase 2: read A m0-3 kk1 + B kk1; stage A-kk0(t+2) into Ac ----
    #pragma unroll
    for (int m = 0; m < 4; ++m) aa[m] = rdfrag(Ac + 16384, wr * 128 + m * 16 + llo, lhi);
    #pragma unroll
    for (int n = 0; n < 4; ++n) bb[n] = rdfrag(Bc + 16384, wc * 64 + n * 16 + llo, lhi);
    if (t + 2 < nt) stage_chunk8(A, row0, K, (long)(t + 2) * 64, Ac, tid);
    BARSB(); LGKM0();
    __builtin_amdgcn_s_setprio(1);
    #pragma unroll
    for (int m = 0; m < 4; ++m)
      #pragma unroll
      for (int n = 0; n < 4; ++n)
        acc[m][n] = __builtin_amdgcn_mfma_f32_16x16x32_bf16(aa[m], bb[n], acc[m][n], 0, 0, 0);
    __builtin_amdgcn_s_setprio(0);
    BARSB();
    // ---- phase 3: read A m4-7 kk1; stage B-kk1(t+2) into Bc+16384 ----
    #pragma unroll
    for (int m = 0; m < 4; ++m) aa[m] = rdfrag(Ac + 16384, wr * 128 + 64 + m * 16 + llo, lhi);
    if (t + 2 < nt) stage_chunk8(W, col0, K, (long)(t + 2) * 64 + 32, Bc + 16384, tid);
    BARSB(); LGKM0();
    __builtin_amdgcn_s_setprio(1);
    #pragma unroll
    for (int m = 0; m < 4; ++m)
      #pragma unroll
      for (int n = 0; n < 4; ++n)
        acc[m + 4][n] = __builtin_amdgcn_mfma_f32_16x16x32_bf16(aa[m], bb[n], acc[m + 4][n], 0, 0, 0);
    __builtin_amdgcn_s_setprio(0);
    // W_b: covers kk0(t+1) (B0 issued ph1(t-1), A0 issued ph2(t-1): >=5 phases lead)
    if (t <= nt - 3)      { asm volatile("s_waitcnt vmcnt(10)" ::: "memory"); }
    else if (t == nt - 2) { asm volatile("s_waitcnt vmcnt(4)"  ::: "memory"); }
    else                  { asm volatile("s_waitcnt vmcnt(0)"  ::: "memory"); }
    BARSB();
  }

  #pragma unroll
  for (int mi = 0; mi < 8; ++mi) {
    #pragma unroll
    for (int rg = 0; rg < 4; ++rg) {
      long row = row0 + wr * 128 + mi * 16 + lhi * 4 + rg;
      #pragma unroll
      for (int n = 0; n < 4; ++n) {
        long col = col0 + wc * 64 + n * 16 + llo;
        float v = acc[mi][n][rg];
        if (EPI == 0) {
          if (col < nreal) ((float*)Cout)[row * (long)ldc + col] = v;
        } else if (EPI == 2) {
          float gl = 0.5f * v * (1.0f + erff(v * 0.70710678118654752440f));
          ((unsigned short*)Cout)[row * (long)ldc + col] = f2bf(gl);
        } else {
          ((unsigned short*)Cout)[row * (long)ldc + col] = f2bf(v);
        }
      }
    }
  }
}

// ---------------- MFMA flash attention ----------------
__global__ __launch_bounds__(256) void flash_attn_kernel(const unsigned short* __restrict__ qkv,
                                                         unsigned short* __restrict__ y) {
  __shared__ unsigned short Kls[64 * 64];
  __shared__ unsigned short Vtls[64 * 64];
  __shared__ unsigned short Pls[4][16 * 64];
  const int tid = threadIdx.x, wave = tid >> 6, lane = tid & 63;
  const int qt = blockIdx.x;
  const int h = blockIdx.y & (H_NUM - 1), b = blockIdx.y >> 4;
  const int q0 = qt * 64;
  const int lhi = lane >> 4, llo = lane & 15;

  const int qrow = q0 + wave * 16 + llo;
  const unsigned short* qptr =
      qkv + ((size_t)(b * T_LEN + qrow)) * 3072 + h * HD_DIM + lhi * 8;
  const bf16x8 qa0 = *(const bf16x8*)qptr;
  const bf16x8 qa1 = *(const bf16x8*)(qptr + 32);

  f32x4 o[4] = {};
  float m[4] = {-1e30f, -1e30f, -1e30f, -1e30f};
  float l[4] = {0.f, 0.f, 0.f, 0.f};

  const unsigned short* kg = qkv + (size_t)b * T_LEN * 3072 + D_DIM + h * HD_DIM;
  const unsigned short* vg = kg + D_DIM;

  const int krow = tid >> 2, kcol = (tid & 3) * 16;
  const int vs0 = (tid >> 3) * 2, vd0 = (tid & 7) * 8;

  const int ntiles = qt + 1;
  for (int st = 0; st < ntiles; ++st) {
    const int s0 = st * 64;
    {
      const unsigned short* src = kg + (size_t)(s0 + krow) * 3072 + kcol;
      u16x8 a = *(const u16x8*)src;
      u16x8 c = *(const u16x8*)(src + 8);
      int base = krow * 128 + kcol * 2;
      int sw = (krow & 7) << 4;
      *(u16x8*)((char*)Kls + ((base) ^ sw))      = a;
      *(u16x8*)((char*)Kls + ((base + 16) ^ sw)) = c;
    }
    {
      const unsigned short* src = vg + (size_t)(s0 + vs0) * 3072 + vd0;
      u16x8 a = *(const u16x8*)src;
      u16x8 c = *(const u16x8*)(src + 3072);
      #pragma unroll
      for (int j = 0; j < 8; ++j) {
        int d = vd0 + j;
        unsigned val = (unsigned)a[j] | ((unsigned)c[j] << 16);
        *(unsigned*)((char*)Vtls + ((d * 128 + vs0 * 2) ^ ((d & 7) << 4))) = val;
      }
    }
    __syncthreads();

    f32x4 s_acc[4] = {};
    #pragma unroll
    for (int kt = 0; kt < 4; ++kt) {
      int kr = kt * 16 + llo;
      int sw = (kr & 7) << 4;
      bf16x8 kb0 = *(const bf16x8*)((char*)Kls + ((kr * 128 + lhi * 16) ^ sw));
      bf16x8 kb1 = *(const bf16x8*)((char*)Kls + ((kr * 128 + 64 + lhi * 16) ^ sw));
      s_acc[kt] = __builtin_amdgcn_mfma_f32_16x16x32_bf16(qa0, kb0, s_acc[kt], 0, 0, 0);
      s_acc[kt] = __builtin_amdgcn_mfma_f32_16x16x32_bf16(qa1, kb1, s_acc[kt], 0, 0, 0);
    }

    float p[4][4];
    float tmax[4] = {-1e30f, -1e30f, -1e30f, -1e30f};
    const int qg = q0 + wave * 16 + lhi * 4;
    #pragma unroll
    for (int kt = 0; kt < 4; ++kt) {
      int ks = s0 + kt * 16 + llo;
      #pragma unroll
      for (int r = 0; r < 4; ++r) {
        float sv = (ks <= qg + r) ? s_acc[kt][r] * 0.125f : -1e30f;
        p[kt][r] = sv;
        tmax[r] = fmaxf(tmax[r], sv);
      }
    }
    #pragma unroll
    for (int r = 0; r < 4; ++r) {
      #pragma unroll
      for (int off = 1; off < 16; off <<= 1)
        tmax[r] = fmaxf(tmax[r], __shfl_xor(tmax[r], off));
      float mn = fmaxf(m[r], tmax[r]);
      float corr = __expf(m[r] - mn);
      m[r] = mn;
      float ps = 0.f;
      #pragma unroll
      for (int kt = 0; kt < 4; ++kt) {
        p[kt][r] = __expf(p[kt][r] - mn);
        ps += p[kt][r];
      }
      #pragma unroll
      for (int off = 1; off < 16; off <<= 1)
        ps += __shfl_xor(ps, off);
      l[r] = l[r] * corr + ps;
      #pragma unroll
      for (int dt = 0; dt < 4; ++dt) o[dt][r] *= corr;
    }

    unsigned short* pw = Pls[wave];
    #pragma unroll
    for (int r = 0; r < 4; ++r) {
      int q = lhi * 4 + r;
      int sw = (q & 7) << 4;
      #pragma unroll
      for (int kt = 0; kt < 4; ++kt) {
        int k = kt * 16 + llo;
        *(unsigned short*)((char*)pw + ((q * 128 + k * 2) ^ sw)) = f2bf(p[kt][r]);
      }
    }
    asm volatile("s_waitcnt lgkmcnt(0)" ::: "memory");

    int psw = (llo & 7) << 4;
    bf16x8 pa0 = *(const bf16x8*)((char*)pw + ((llo * 128 + lhi * 16) ^ psw));
    bf16x8 pa1 = *(const bf16x8*)((char*)pw + ((llo * 128 + 64 + lhi * 16) ^ psw));
    #pragma unroll
    for (int dt = 0; dt < 4; ++dt) {
      int vr = dt * 16 + llo;
      int sw = (vr & 7) << 4;
      bf16x8 vb0 = *(const bf16x8*)((char*)Vtls + ((vr * 128 + lhi * 16) ^ sw));
      bf16x8 vb1 = *(const bf16x8*)((char*)Vtls + ((vr * 128 + 64 + lhi * 16) ^ sw));
      o[dt] = __builtin_amdgcn_mfma_f32_16x16x32_bf16(pa0, vb0, o[dt], 0, 0, 0);
      o[dt] = __builtin_amdgcn_mfma_f32_16x16x32_bf16(pa1, vb1, o[dt], 0, 0, 0);
    }
    __syncthreads();
  }

  #pragma unroll
  for (int r = 0; r < 4; ++r) {
    long row = q0 + wave * 16 + lhi * 4 + r;
    float inv = 1.0f / l[r];
    #pragma unroll
    for (int dt = 0; dt < 4; ++dt) {
      long col = h * HD_DIM + dt * 16 + llo;
      y[(row + (size_t)b * T_LEN) * D_DIM + col] = f2bf(o[dt][r] * inv);
    }
  }
}

// ---------------- loss: single-pass online logsumexp ----------------
__global__ __launch_bounds__(256) void loss_rows_kernel(const float* __restrict__ logits,
                                                        const int* __restrict__ tgt,
                                                        float* __restrict__ nll,
                                                        float* __restrict__ vld) {
  int r = blockIdx.x;
  int tid = threadIdx.x;
  const float* row = logits + (size_t)r * V_SIZE;
  float lm = -1e30f, ls = 0.f;
  for (int i = tid; i < V_SIZE; i += 256) {
    float v = row[i];
    float nm = fmaxf(lm, v);
    ls = ls * __expf(lm - nm) + __expf(v - nm);
    lm = nm;
  }
  #pragma unroll
  for (int off = 1; off < 64; off <<= 1) {
    float om = __shfl_xor(lm, off);
    float os = __shfl_xor(ls, off);
    float nm = fmaxf(lm, om);
    ls = ls * __expf(lm - nm) + os * __expf(om - nm);
    lm = nm;
  }
  __shared__ float sm[4], ss[4];
  int w = tid >> 6, lane = tid & 63;
  if (lane == 0) { sm[w] = lm; ss[w] = ls; }
  __syncthreads();
  if (tid == 0) {
    lm = sm[0]; ls = ss[0];
    #pragma unroll
    for (int i = 1; i < 4; ++i) {
      float nm = fmaxf(lm, sm[i]);
      ls = ls * __expf(lm - nm) + ss[i] * __expf(sm[i] - nm);
      lm = nm;
    }
    int tg = tgt[r];
    if (tg != -1) { nll[r] = lm + logf(ls) - row[tg]; vld[r] = 1.0f; }
    else          { nll[r] = 0.f;                     vld[r] = 0.f; }
  }
}

__global__ __launch_bounds__(256) void loss_reduce_kernel(const float* __restrict__ nll,
                                                          const float* __restrict__ vld,
                                                          float* __restrict__ out) {
  int tid = threadIdx.x;
  float s = 0.f, c = 0.f;
  for (int i = tid; i < M_ROWS; i += 256) { s += nll[i]; c += vld[i]; }
  #pragma unroll
  for (int off = 32; off; off >>= 1) { s += __shfl_xor(s, off); c += __shfl_xor(c, off); }
  __shared__ float s1[4], s2[4];
  int w = tid >> 6, lane = tid & 63;
  if (lane == 0) { s1[w] = s; s2[w] = c; }
  __syncthreads();
  if (tid == 0) {
    s = s1[0] + s1[1] + s1[2] + s1[3];
    c = s2[0] + s2[1] + s2[2] + s2[3];
    out[0] = s / fmaxf(c, 1.0f);
  }
}

extern "C" void kernel_launch(void* const* d_in, const int* in_sizes, int n_in,
                              void* d_out, int out_size, void* d_ws, size_t ws_size,
                              hipStream_t stream) {
  const int*   ctx    = (const int*)d_in[0];
  const int*   tgt    = (const int*)d_in[1];
  const float* wte    = (const float*)d_in[2];
  const float* wpe    = (const float*)d_in[3];
  const float* ln1_g  = (const float*)d_in[4];
  const float* ln1_b  = (const float*)d_in[5];
  const float* w_attn = (const float*)d_in[6];
  const float* w_proj = (const float*)d_in[7];
  const float* ln2_g  = (const float*)d_in[8];
  const float* ln2_b  = (const float*)d_in[9];
  const float* w_fc   = (const float*)d_in[10];
  const float* w_out  = (const float*)d_in[11];
  const float* lnf_g  = (const float*)d_in[12];
  const float* lnf_b  = (const float*)d_in[13];

  float* outp   = (float*)d_out;
  float* logits = outp;
  float* loss   = outp + (size_t)M_ROWS * V_SIZE;

  // ---- workspace layout (bytes), max ~128.5 MB ----
  char* ws = (char*)d_ws;
  float*          x      = (float*)(ws + 0);                    // fp32 [4096][1024]
  unsigned short* xn     = (unsigned short*)(ws + 16777216);    // bf16 [4096][1024]
  unsigned short* qkv    = (unsigned short*)(ws + 25165824);    // bf16 [4096][3072]
  unsigned short* y      = (unsigned short*)(ws + 50331648);    // bf16 [4096][1024]
  unsigned short* h      = (unsigned short*)(ws + 58720256);    // bf16 [4096][4096]
  unsigned short* wa_bf  = (unsigned short*)(ws + 92274688);
  unsigned short* wp_bf  = (unsigned short*)(ws + 98566144);
  unsigned short* wf_bf  = (unsigned short*)(ws + 100663296);
  unsigned short* wo_bf  = (unsigned short*)(ws + 109051904);
  unsigned short* wte_bf = (unsigned short*)(ws + 25165824);    // alias post-loop [50432][1024]
  float*          nll    = (float*)(ws + 128450560);
  float*          vld    = (float*)(ws + 128466944);

  embed_kernel<<<(M_ROWS * D_DIM + 255) / 256, 256, 0, stream>>>(ctx, wte, wpe, x);

  for (int l = 0; l < L_NUM; ++l) {
    conv_layer_kernel<<<6144, 256, 0, stream>>>(
        w_attn + (size_t)l * 3 * D_DIM * D_DIM, w_proj + (size_t)l * D_DIM * D_DIM,
        w_fc + (size_t)l * 4 * D_DIM * D_DIM, w_out + (size_t)l * D_DIM * 4 * D_DIM,
        wa_bf, wp_bf, wf_bf, wo_bf);
    layernorm_kernel<<<M_ROWS, 256, 0, stream>>>(x, ln1_g + l * D_DIM, ln1_b + l * D_DIM, xn);
    gemm8p<3><<<12 * 16, 512, 0, stream>>>(
        xn, wa_bf, qkv, D_DIM, 3 * D_DIM, 3 * D_DIM, 16, 1);
    flash_attn_kernel<<<dim3(T_LEN / 64, B_NUM * H_NUM), 256, 0, stream>>>(qkv, y);
    mfma_gemm<1><<<dim3(D_DIM / 128, M_ROWS / 128), 256, 0, stream>>>(
        y, wp_bf, x, x, D_DIM, D_DIM, D_DIM);
    layernorm_kernel<<<M_ROWS, 256, 0, stream>>>(x, ln2_g + l * D_DIM, ln2_b + l * D_DIM, xn);
    gemm8p<2><<<16 * 16, 512, 0, stream>>>(
        xn, wf_bf, h, D_DIM, 4 * D_DIM, 4 * D_DIM, 16, 1);
    mfma_gemm<1><<<dim3(D_DIM / 128, M_ROWS / 128), 256, 0, stream>>>(
        h, wo_bf, x, x, 4 * D_DIM, D_DIM, D_DIM);
  }

  layernorm_kernel<<<M_ROWS, 256, 0, stream>>>(x, lnf_g, lnf_b, xn);
  conv_kernel<<<25129, 256, 0, stream>>>(wte, wte_bf, (long)V_SIZE * D_DIM);
  hipMemsetAsync(wte_bf + (size_t)V_SIZE * D_DIM, 0,
                 (size_t)(V_PAD - V_SIZE) * D_DIM * sizeof(unsigned short), stream);
  gemm8p<0><<<197 * 16, 512, 0, stream>>>(
      xn, wte_bf, logits, D_DIM, V_SIZE, V_SIZE, 16, 1);
  loss_rows_kernel<<<M_ROWS, 256, 0, stream>>>(logits, tgt, nll, vld);
  loss_reduce_kernel<<<1, 256, 0, stream>>>(nll, vld, loss);
}

// Round 7
// 3442.910 us; speedup vs baseline: 13.2236x; 1.0136x over previous
//
#include <hip/hip_runtime.h>
#include <cstdint>

#define V_SIZE 50257
#define V_PAD  50432            // 197 * 256
#define D_DIM  1024
#define H_NUM  16
#define L_NUM  8
#define T_LEN  1024
#define B_NUM  4
#define HD_DIM 64
#define M_ROWS 4096
#define LN_EPS 1e-5f

typedef __attribute__((ext_vector_type(8))) __bf16 bf16x8;
typedef __attribute__((ext_vector_type(4))) float f32x4;
typedef __attribute__((ext_vector_type(8))) unsigned short u16x8;

__device__ __forceinline__ unsigned short f2bf(float f) {
  unsigned u = __builtin_bit_cast(unsigned, f);
  u += 0x7fffu + ((u >> 16) & 1u);   // RNE
  return (unsigned short)(u >> 16);
}

__device__ __forceinline__ void gload_lds16(const void* g, void* l) {
  typedef const __attribute__((address_space(1))) unsigned int* gp_t;
  typedef __attribute__((address_space(3))) unsigned int* lp_t;
  __builtin_amdgcn_global_load_lds((gp_t)g, (lp_t)l, 16, 0, 0);
}

__device__ __forceinline__ f32x4 mfma16(bf16x8 a, bf16x8 b, f32x4 c) {
  return __builtin_amdgcn_mfma_f32_16x16x32_bf16(a, b, c, 0, 0, 0);
}

#define BARSB() { __builtin_amdgcn_s_barrier(); __builtin_amdgcn_sched_barrier(0); }
#define SCHB()  __builtin_amdgcn_sched_barrier(0)

// ---------------- embedding ----------------
__global__ __launch_bounds__(256) void embed_kernel(const int* __restrict__ ctx,
                                                    const float* __restrict__ wte,
                                                    const float* __restrict__ wpe,
                                                    float* __restrict__ x) {
  int i = blockIdx.x * blockDim.x + threadIdx.x;
  if (i >= M_ROWS * D_DIM) return;
  int bt = i / D_DIM, d = i - bt * D_DIM;
  int t = bt & (T_LEN - 1);
  x[i] = wte[(size_t)ctx[bt] * D_DIM + d] + wpe[(size_t)t * D_DIM + d];
}

// ---------------- fp32 -> bf16 weight conversion ----------------
__global__ __launch_bounds__(256) void conv_layer_kernel(const float* __restrict__ wa,
                                                         const float* __restrict__ wp,
                                                         const float* __restrict__ wf,
                                                         const float* __restrict__ wo,
                                                         unsigned short* __restrict__ oa,
                                                         unsigned short* __restrict__ op,
                                                         unsigned short* __restrict__ of,
                                                         unsigned short* __restrict__ oo) {
  long i = (long)(blockIdx.x * 256 + threadIdx.x) * 8;
  const float* src; unsigned short* dst; long off;
  if (i < 3145728L)      { src = wa; dst = oa; off = i; }
  else if (i < 4194304L) { src = wp; dst = op; off = i - 3145728L; }
  else if (i < 8388608L) { src = wf; dst = of; off = i - 4194304L; }
  else                   { src = wo; dst = oo; off = i - 8388608L; }
  float4 v0 = *(const float4*)(src + off);
  float4 v1 = *(const float4*)(src + off + 4);
  u16x8 o;
  o[0] = f2bf(v0.x); o[1] = f2bf(v0.y); o[2] = f2bf(v0.z); o[3] = f2bf(v0.w);
  o[4] = f2bf(v1.x); o[5] = f2bf(v1.y); o[6] = f2bf(v1.z); o[7] = f2bf(v1.w);
  *(u16x8*)(dst + off) = o;
}

__global__ __launch_bounds__(256) void conv_kernel(const float* __restrict__ in,
                                                   unsigned short* __restrict__ out, long n) {
  long i = (long)(blockIdx.x * 256 + threadIdx.x) * 8;
  if (i >= n) return;
  float4 v0 = *(const float4*)(in + i);
  float4 v1 = *(const float4*)(in + i + 4);
  u16x8 o;
  o[0] = f2bf(v0.x); o[1] = f2bf(v0.y); o[2] = f2bf(v0.z); o[3] = f2bf(v0.w);
  o[4] = f2bf(v1.x); o[5] = f2bf(v1.y); o[6] = f2bf(v1.z); o[7] = f2bf(v1.w);
  *(u16x8*)(out + i) = o;
}

// ---------------- layernorm: fp32 in -> bf16 out ----------------
__global__ __launch_bounds__(256) void layernorm_kernel(const float* __restrict__ x,
                                                        const float* __restrict__ g,
                                                        const float* __restrict__ b,
                                                        unsigned short* __restrict__ o) {
  int r = blockIdx.x;
  int tid = threadIdx.x;
  const float* row = x + (size_t)r * D_DIM;
  float4 v = *(const float4*)(row + tid * 4);
  float s  = v.x + v.y + v.z + v.w;
  float s2 = v.x * v.x + v.y * v.y + v.z * v.z + v.w * v.w;
  #pragma unroll
  for (int off = 32; off; off >>= 1) {
    s  += __shfl_xor(s, off);
    s2 += __shfl_xor(s2, off);
  }
  __shared__ float a1[4], a2[4];
  int w = tid >> 6, lane = tid & 63;
  if (lane == 0) { a1[w] = s; a2[w] = s2; }
  __syncthreads();
  s  = a1[0] + a1[1] + a1[2] + a1[3];
  s2 = a2[0] + a2[1] + a2[2] + a2[3];
  float mu  = s * (1.0f / D_DIM);
  float var = s2 * (1.0f / D_DIM) - mu * mu;
  float rs  = rsqrtf(var + LN_EPS);
  int d = tid * 4;
  float4 gv = *(const float4*)(g + d);
  float4 bv = *(const float4*)(b + d);
  ushort4 ov;
  ov.x = f2bf((v.x - mu) * rs * gv.x + bv.x);
  ov.y = f2bf((v.y - mu) * rs * gv.y + bv.y);
  ov.z = f2bf((v.z - mu) * rs * gv.z + bv.z);
  ov.w = f2bf((v.w - mu) * rs * gv.w + bv.w);
  *(ushort4*)(o + (size_t)r * D_DIM + d) = ov;
}

// ---------------- m97-structure 128x128 bf16 MFMA GEMM (proj/out) ----------
template<int EPI>
__global__ __launch_bounds__(256) void mfma_gemm(const unsigned short* __restrict__ A,
                                                 const unsigned short* __restrict__ W,
                                                 const float* R, void* Cout,
                                                 int K, int ldc, int nreal) {
  __shared__ unsigned short As[128 * 32];
  __shared__ unsigned short Bs[128 * 32];
  const int tid  = threadIdx.x;
  const int wave = tid >> 6, lane = tid & 63;
  const int wr = wave >> 1, wc = wave & 1;
  const long row0 = (long)blockIdx.y * 128;
  const long col0 = (long)blockIdx.x * 128;
  f32x4 acc[4][4] = {};
  const int frow = lane & 15;
  const int fk   = (lane >> 4) * 8;
  const int b0 = wave * 2048 + lane * 16;
  for (int k0 = 0; k0 < K; k0 += 32) {
    #pragma unroll
    for (int c = 0; c < 2; ++c) {
      int b = b0 + c * 1024;
      int r = b >> 6, ke = (b & 63) >> 1;
      gload_lds16(A + (row0 + r) * (long)K + k0 + ke, (char*)As + b);
      gload_lds16(W + (col0 + r) * (long)K + k0 + ke, (char*)Bs + b);
    }
    __syncthreads();
    bf16x8 af[4], bfr[4];
    #pragma unroll
    for (int i = 0; i < 4; ++i)
      af[i] = *(const bf16x8*)(As + (wr * 64 + i * 16 + frow) * 32 + fk);
    #pragma unroll
    for (int j = 0; j < 4; ++j)
      bfr[j] = *(const bf16x8*)(Bs + (wc * 64 + j * 16 + frow) * 32 + fk);
    #pragma unroll
    for (int i = 0; i < 4; ++i)
      #pragma unroll
      for (int j = 0; j < 4; ++j)
        acc[i][j] = mfma16(af[i], bfr[j], acc[i][j]);
    __syncthreads();
  }
  const int crow = (lane >> 4) * 4;
  const int ccol = lane & 15;
  #pragma unroll
  for (int i = 0; i < 4; ++i) {
    #pragma unroll
    for (int r = 0; r < 4; ++r) {
      long row = row0 + wr * 64 + i * 16 + crow + r;
      #pragma unroll
      for (int j = 0; j < 4; ++j) {
        long col = col0 + wc * 64 + j * 16 + ccol;
        float v = acc[i][j][r];
        if (EPI == 1) {
          ((float*)Cout)[row * (long)ldc + col] = v + R[row * (long)ldc + col];
        } else {
          ((float*)Cout)[row * (long)ldc + col] = v;
        }
      }
    }
  }
}

// ---------------- 256x256 software-pipelined bf16 GEMM (qkv/fc/logits) ----------
// Reads for phase p+1 issue in slot p (register dbuf aa0/aa1/bb0/bb1); counted
// lgkmcnt waits only the PREVIOUS slot's reads -> LDS drain overlaps MFMA.
// One barrier per slot (4/K-tile, was 8). Stage plan (iter t):
//   S0: A1(t+1) | S1: B0(t+2) | S2: A0(t+2) | S3: B1(t+2)
// vmcnt: W1 end-S0 = 8 (covers kk1(t), >=4-slot lead); W2 end-S2 = 8/4/0
// (covers kk0(t+1)). Overwrite hazards each closed by the lgkm wait + barrier
// one slot before the stage (ledger in session notes). Requires nt >= 3.
__device__ __forceinline__ void stage_chunk8(const unsigned short* __restrict__ base,
                                             long rbase, int K, long gk,
                                             char* cb, int tid) {
  #pragma unroll
  for (int j = 0; j < 2; ++j) {
    int db = j * 8192 + tid * 16;
    int lb = db ^ (((db >> 7) & 3) << 4);
    long r = lb >> 6;
    int e = (lb & 63) >> 1;
    gload_lds16(base + (rbase + r) * (long)K + gk + e, cb + db);
  }
}

__device__ __forceinline__ bf16x8 rdfrag(const char* cb, int rr, int lhi) {
  int p = (rr << 6) + (lhi << 4);
  p ^= ((rr >> 1) & 3) << 4;
  return *(const bf16x8*)(cb + p);
}

template<int EPI>
__global__ __launch_bounds__(512, 1) void gemm8p(const unsigned short* __restrict__ A,
                                                 const unsigned short* __restrict__ W,
                                                 void* Cout, int K, int ldc, int nreal,
                                                 int nbx, int xcd) {
  __shared__ char lds[131072];
  const int tid  = threadIdx.x;
  const int lane = tid & 63;
  const int wave = tid >> 6;
  const int wr = wave >> 2, wc = wave & 3;
  const int lhi = lane >> 4, llo = lane & 15;
  int bid = blockIdx.x;
  if (xcd) { int per = (int)gridDim.x >> 3; bid = (bid & 7) * per + (bid >> 3); }
  const int brow = bid % nbx;
  const int bcol = bid / nbx;
  const long row0 = (long)brow * 256;
  const long col0 = (long)bcol * 256;
  char* Ab0 = (char*)lds;
  char* Bb0 = (char*)lds + 65536;
  const int nt = K >> 6;   // nt >= 3 assumed (all uses: nt = 16)

  // prologue stages (issue order matters for vmcnt ledger):
  // B0(0),A0(0),B1(0),A1(0),B0(1),A0(1),B1(1) = 14 loads
  stage_chunk8(W, col0, K, 0,  Bb0,         tid);
  stage_chunk8(A, row0, K, 0,  Ab0,         tid);
  stage_chunk8(W, col0, K, 32, Bb0 + 16384, tid);
  stage_chunk8(A, row0, K, 32, Ab0 + 16384, tid);
  stage_chunk8(W, col0, K, 64, Bb0 + 32768, tid);
  stage_chunk8(A, row0, K, 64, Ab0 + 32768, tid);
  stage_chunk8(W, col0, K, 96, Bb0 + 49152, tid);
  asm volatile("s_waitcnt vmcnt(10)" ::: "memory");   // kk0(0) confirmed
  BARSB();

  const int arow  = wr * 128 + llo;
  const int brow_ = wc * 64 + llo;

  bf16x8 aa0[4], aa1[4], bb0[4], bb1[4];
  // prologue reads: ph0(0) operands (kk0(0))
  #pragma unroll
  for (int m = 0; m < 4; ++m) aa0[m] = rdfrag(Ab0, arow + m * 16, lhi);
  #pragma unroll
  for (int n = 0; n < 4; ++n) bb0[n] = rdfrag(Bb0, brow_ + n * 16, lhi);

  f32x4 acc[8][4] = {};
  for (int t = 0; t < nt; ++t) {
    char* Ac = Ab0 + (t & 1) * 32768;
    char* Bc = Bb0 + (t & 1) * 32768;
    char* An = Ab0 + ((t + 1) & 1) * 32768;
    char* Bn = Bb0 + ((t + 1) & 1) * 32768;
    // ===== S0: reads aa1<-A m4-7 kk0 | stage A1(t+1) | MFMA ph0 | W1 | bar
    #pragma unroll
    for (int m = 0; m < 4; ++m) aa1[m] = rdfrag(Ac, arow + 64 + m * 16, lhi);
    asm volatile("s_waitcnt lgkmcnt(4)" ::: "memory");  // prev-slot reads done
    SCHB();
    if (t + 1 < nt) stage_chunk8(A, row0, K, (long)(t + 1) * 64 + 32, An + 16384, tid);
    __builtin_amdgcn_s_setprio(1);
    #pragma unroll
    for (int m = 0; m < 4; ++m)
      #pragma unroll
      for (int n = 0; n < 4; ++n)
        acc[m][n] = mfma16(aa0[m], bb0[n], acc[m][n]);
    __builtin_amdgcn_s_setprio(0);
    SCHB();
    if (t < nt - 1) { asm volatile("s_waitcnt vmcnt(8)" ::: "memory"); }
    else            { asm volatile("s_waitcnt vmcnt(0)" ::: "memory"); }
    BARSB();
    // ===== S1: reads aa0<-A m0-3 kk1, bb1<-B kk1 | stage B0(t+2) | MFMA ph1 | bar
    #pragma unroll
    for (int m = 0; m < 4; ++m) aa0[m] = rdfrag(Ac + 16384, arow + m * 16, lhi);
    #pragma unroll
    for (int n = 0; n < 4; ++n) bb1[n] = rdfrag(Bc + 16384, brow_ + n * 16, lhi);
    asm volatile("s_waitcnt lgkmcnt(8)" ::: "memory");
    SCHB();
    if (t + 2 < nt) stage_chunk8(W, col0, K, (long)(t + 2) * 64, Bc, tid);
    __builtin_amdgcn_s_setprio(1);
    #pragma unroll
    for (int m = 0; m < 4; ++m)
      #pragma unroll
      for (int n = 0; n < 4; ++n)
        acc[m + 4][n] = mfma16(aa1[m], bb0[n], acc[m + 4][n]);
    __builtin_amdgcn_s_setprio(0);
    SCHB();
    BARSB();
    // ===== S2: reads aa1<-A m4-7 kk1 | stage A0(t+2) | MFMA ph2 | W2 | bar
    #pragma unroll
    for (int m = 0; m < 4; ++m) aa1[m] = rdfrag(Ac + 16384, arow + 64 + m * 16, lhi);
    asm volatile("s_waitcnt lgkmcnt(4)" ::: "memory");
    SCHB();
    if (t + 2 < nt) stage_chunk8(A, row0, K, (long)(t + 2) * 64, Ac, tid);
    __builtin_amdgcn_s_setprio(1);
    #pragma unroll
    for (int m = 0; m < 4; ++m)
      #pragma unroll
      for (int n = 0; n < 4; ++n)
        acc[m][n] = mfma16(aa0[m], bb1[n], acc[m][n]);
    __builtin_amdgcn_s_setprio(0);
    SCHB();
    if (t <= nt - 3)      { asm volatile("s_waitcnt vmcnt(8)" ::: "memory"); }
    else if (t == nt - 2) { asm volatile("s_waitcnt vmcnt(4)" ::: "memory"); }
    else                  { asm volatile("s_waitcnt vmcnt(0)" ::: "memory"); }
    BARSB();
    // ===== S3: reads aa0,bb0<-kk0(t+1) | stage B1(t+2) | MFMA ph3 | bar
    if (t + 1 < nt) {
      #pragma unroll
      for (int m = 0; m < 4; ++m) aa0[m] = rdfrag(An, arow + m * 16, lhi);
      #pragma unroll
      for (int n = 0; n < 4; ++n) bb0[n] = rdfrag(Bn, brow_ + n * 16, lhi);
      asm volatile("s_waitcnt lgkmcnt(8)" ::: "memory");
    } else {
      asm volatile("s_waitcnt lgkmcnt(0)" ::: "memory");
    }
    SCHB();
    if (t + 2 < nt) stage_chunk8(W, col0, K, (long)(t + 2) * 64 + 32, Bc + 16384, tid);
    __builtin_amdgcn_s_setprio(1);
    #pragma unroll
    for (int m = 0; m < 4; ++m)
      #pragma unroll
      for (int n = 0; n < 4; ++n)
        acc[m + 4][n] = mfma16(aa1[m], bb1[n], acc[m + 4][n]);
    __builtin_amdgcn_s_setprio(0);
    SCHB();
    BARSB();
  }

  // ---- epilogue: C/D layout col=lane&15, row=(lane>>4)*4+reg ----
  #pragma unroll
  for (int mi = 0; mi < 8; ++mi) {
    #pragma unroll
    for (int rg = 0; rg < 4; ++rg) {
      long row = row0 + wr * 128 + mi * 16 + lhi * 4 + rg;
      #pragma unroll
      for (int n = 0; n < 4; ++n) {
        long col = col0 + wc * 64 + n * 16 + llo;
        float v = acc[mi][n][rg];
        if (EPI == 0) {
          if (col < nreal) ((float*)Cout)[row * (long)ldc + col] = v;
        } else if (EPI == 2) {
          float gl = 0.5f * v * (1.0f + erff(v * 0.70710678118654752440f));
          ((unsigned short*)Cout)[row * (long)ldc + col] = f2bf(gl);
        } else {
          ((unsigned short*)Cout)[row * (long)ldc + col] = f2bf(v);
        }
      }
    }
  }
}

// ---------------- MFMA flash attention ----------------
__global__ __launch_bounds__(256) void flash_attn_kernel(const unsigned short* __restrict__ qkv,
                                                         unsigned short* __restrict__ y) {
  __shared__ unsigned short Kls[64 * 64];
  __shared__ unsigned short Vtls[64 * 64];
  __shared__ unsigned short Pls[4][16 * 64];
  const int tid = threadIdx.x, wave = tid >> 6, lane = tid & 63;
  const int qt = blockIdx.x;
  const int h = blockIdx.y & (H_NUM - 1), b = blockIdx.y >> 4;
  const int q0 = qt * 64;
  const int lhi = lane >> 4, llo = lane & 15;

  const int qrow = q0 + wave * 16 + llo;
  const unsigned short* qptr =
      qkv + ((size_t)(b * T_LEN + qrow)) * 3072 + h * HD_DIM + lhi * 8;
  const bf16x8 qa0 = *(const bf16x8*)qptr;
  const bf16x8 qa1 = *(const bf16x8*)(qptr + 32);

  f32x4 o[4] = {};
  float m[4] = {-1e30f, -1e30f, -1e30f, -1e30f};
  float l[4] = {0.f, 0.f, 0.f, 0.f};

  const unsigned short* kg = qkv + (size_t)b * T_LEN * 3072 + D_DIM + h * HD_DIM;
  const unsigned short* vg = kg + D_DIM;

  const int krow = tid >> 2, kcol = (tid & 3) * 16;
  const int vs0 = (tid >> 3) * 2, vd0 = (tid & 7) * 8;

  const int ntiles = qt + 1;
  for (int st = 0; st < ntiles; ++st) {
    const int s0 = st * 64;
    {
      const unsigned short* src = kg + (size_t)(s0 + krow) * 3072 + kcol;
      u16x8 a = *(const u16x8*)src;
      u16x8 c = *(const u16x8*)(src + 8);
      int base = krow * 128 + kcol * 2;
      int sw = (krow & 7) << 4;
      *(u16x8*)((char*)Kls + ((base) ^ sw))      = a;
      *(u16x8*)((char*)Kls + ((base + 16) ^ sw)) = c;
    }
    {
      const unsigned short* src = vg + (size_t)(s0 + vs0) * 3072 + vd0;
      u16x8 a = *(const u16x8*)src;
      u16x8 c = *(const u16x8*)(src + 3072);
      #pragma unroll
      for (int j = 0; j < 8; ++j) {
        int d = vd0 + j;
        unsigned val = (unsigned)a[j] | ((unsigned)c[j] << 16);
        *(unsigned*)((char*)Vtls + ((d * 128 + vs0 * 2) ^ ((d & 7) << 4))) = val;
      }
    }
    __syncthreads();

    f32x4 s_acc[4] = {};
    #pragma unroll
    for (int kt = 0; kt < 4; ++kt) {
      int kr = kt * 16 + llo;
      int sw = (kr & 7) << 4;
      bf16x8 kb0 = *(const bf16x8*)((char*)Kls + ((kr * 128 + lhi * 16) ^ sw));
      bf16x8 kb1 = *(const bf16x8*)((char*)Kls + ((kr * 128 + 64 + lhi * 16) ^ sw));
      s_acc[kt] = mfma16(qa0, kb0, s_acc[kt]);
      s_acc[kt] = mfma16(qa1, kb1, s_acc[kt]);
    }

    float p[4][4];
    float tmax[4] = {-1e30f, -1e30f, -1e30f, -1e30f};
    const int qg = q0 + wave * 16 + lhi * 4;
    #pragma unroll
    for (int kt = 0; kt < 4; ++kt) {
      int ks = s0 + kt * 16 + llo;
      #pragma unroll
      for (int r = 0; r < 4; ++r) {
        float sv = (ks <= qg + r) ? s_acc[kt][r] * 0.125f : -1e30f;
        p[kt][r] = sv;
        tmax[r] = fmaxf(tmax[r], sv);
      }
    }
    #pragma unroll
    for (int r = 0; r < 4; ++r) {
      #pragma unroll
      for (int off = 1; off < 16; off <<= 1)
        tmax[r] = fmaxf(tmax[r], __shfl_xor(tmax[r], off));
      float mn = fmaxf(m[r], tmax[r]);
      float corr = __expf(m[r] - mn);
      m[r] = mn;
      float ps = 0.f;
      #pragma unroll
      for (int kt = 0; kt < 4; ++kt) {
        p[kt][r] = __expf(p[kt][r] - mn);
        ps += p[kt][r];
      }
      #pragma unroll
      for (int off = 1; off < 16; off <<= 1)
        ps += __shfl_xor(ps, off);
      l[r] = l[r] * corr + ps;
      #pragma unroll
      for (int dt = 0; dt < 4; ++dt) o[dt][r] *= corr;
    }

    unsigned short* pw = Pls[wave];
    #pragma unroll
    for (int r = 0; r < 4; ++r) {
      int q = lhi * 4 + r;
      int sw = (q & 7) << 4;
      #pragma unroll
      for (int kt = 0; kt < 4; ++kt) {
        int k = kt * 16 + llo;
        *(unsigned short*)((char*)pw + ((q * 128 + k * 2) ^ sw)) = f2bf(p[kt][r]);
      }
    }
    asm volatile("s_waitcnt lgkmcnt(0)" ::: "memory");

    int psw = (llo & 7) << 4;
    bf16x8 pa0 = *(const bf16x8*)((char*)pw + ((llo * 128 + lhi * 16) ^ psw));
    bf16x8 pa1 = *(const bf16x8*)((char*)pw + ((llo * 128 + 64 + lhi * 16) ^ psw));
    #pragma unroll
    for (int dt = 0; dt < 4; ++dt) {
      int vr = dt * 16 + llo;
      int sw = (vr & 7) << 4;
      bf16x8 vb0 = *(const bf16x8*)((char*)Vtls + ((vr * 128 + lhi * 16) ^ sw));
      bf16x8 vb1 = *(const bf16x8*)((char*)Vtls + ((vr * 128 + 64 + lhi * 16) ^ sw));
      o[dt] = mfma16(pa0, vb0, o[dt]);
      o[dt] = mfma16(pa1, vb1, o[dt]);
    }
    __syncthreads();
  }

  #pragma unroll
  for (int r = 0; r < 4; ++r) {
    long row = q0 + wave * 16 + lhi * 4 + r;
    float inv = 1.0f / l[r];
    #pragma unroll
    for (int dt = 0; dt < 4; ++dt) {
      long col = h * HD_DIM + dt * 16 + llo;
      y[(row + (size_t)b * T_LEN) * D_DIM + col] = f2bf(o[dt][r] * inv);
    }
  }
}

// ---------------- loss: single-pass online logsumexp ----------------
__global__ __launch_bounds__(256) void loss_rows_kernel(const float* __restrict__ logits,
                                                        const int* __restrict__ tgt,
                                                        float* __restrict__ nll,
                                                        float* __restrict__ vld) {
  int r = blockIdx.x;
  int tid = threadIdx.x;
  const float* row = logits + (size_t)r * V_SIZE;
  float lm = -1e30f, ls = 0.f;
  for (int i = tid; i < V_SIZE; i += 256) {
    float v = row[i];
    float nm = fmaxf(lm, v);
    ls = ls * __expf(lm - nm) + __expf(v - nm);
    lm = nm;
  }
  #pragma unroll
  for (int off = 1; off < 64; off <<= 1) {
    float om = __shfl_xor(lm, off);
    float os = __shfl_xor(ls, off);
    float nm = fmaxf(lm, om);
    ls = ls * __expf(lm - nm) + os * __expf(om - nm);
    lm = nm;
  }
  __shared__ float sm[4], ss[4];
  int w = tid >> 6, lane = tid & 63;
  if (lane == 0) { sm[w] = lm; ss[w] = ls; }
  __syncthreads();
  if (tid == 0) {
    lm = sm[0]; ls = ss[0];
    #pragma unroll
    for (int i = 1; i < 4; ++i) {
      float nm = fmaxf(lm, sm[i]);
      ls = ls * __expf(lm - nm) + ss[i] * __expf(sm[i] - nm);
      lm = nm;
    }
    int tg = tgt[r];
    if (tg != -1) { nll[r] = lm + logf(ls) - row[tg]; vld[r] = 1.0f; }
    else          { nll[r] = 0.f;                     vld[r] = 0.f; }
  }
}

__global__ __launch_bounds__(256) void loss_reduce_kernel(const float* __restrict__ nll,
                                                          const float* __restrict__ vld,
                                                          float* __restrict__ out) {
  int tid = threadIdx.x;
  float s = 0.f, c = 0.f;
  for (int i = tid; i < M_ROWS; i += 256) { s += nll[i]; c += vld[i]; }
  #pragma unroll
  for (int off = 32; off; off >>= 1) { s += __shfl_xor(s, off); c += __shfl_xor(c, off); }
  __shared__ float s1[4], s2[4];
  int w = tid >> 6, lane = tid & 63;
  if (lane == 0) { s1[w] = s; s2[w] = c; }
  __syncthreads();
  if (tid == 0) {
    s = s1[0] + s1[1] + s1[2] + s1[3];
    c = s2[0] + s2[1] + s2[2] + s2[3];
    out[0] = s / fmaxf(c, 1.0f);
  }
}

extern "C" void kernel_launch(void* const* d_in, const int* in_sizes, int n_in,
                              void* d_out, int out_size, void* d_ws, size_t ws_size,
                              hipStream_t stream) {
  const int*   ctx    = (const int*)d_in[0];
  const int*   tgt    = (const int*)d_in[1];
  const float* wte    = (const float*)d_in[2];
  const float* wpe    = (const float*)d_in[3];
  const float* ln1_g  = (const float*)d_in[4];
  const float* ln1_b  = (const float*)d_in[5];
  const float* w_attn = (const float*)d_in[6];
  const float* w_proj = (const float*)d_in[7];
  const float* ln2_g  = (const float*)d_in[8];
  const float* ln2_b  = (const float*)d_in[9];
  const float* w_fc   = (const float*)d_in[10];
  const float* w_out  = (const float*)d_in[11];
  const float* lnf_g  = (const float*)d_in[12];
  const float* lnf_b  = (const float*)d_in[13];

  float* outp   = (float*)d_out;
  float* logits = outp;
  float* loss   = outp + (size_t)M_ROWS * V_SIZE;

  // ---- workspace layout (bytes), max ~128.5 MB ----
  char* ws = (char*)d_ws;
  float*          x      = (float*)(ws + 0);                    // fp32 [4096][1024]
  unsigned short* xn     = (unsigned short*)(ws + 16777216);    // bf16 [4096][1024]
  unsigned short* qkv    = (unsigned short*)(ws + 25165824);    // bf16 [4096][3072]
  unsigned short* y      = (unsigned short*)(ws + 50331648);    // bf16 [4096][1024]
  unsigned short* h      = (unsigned short*)(ws + 58720256);    // bf16 [4096][4096]
  unsigned short* wa_bf  = (unsigned short*)(ws + 92274688);
  unsigned short* wp_bf  = (unsigned short*)(ws + 98566144);
  unsigned short* wf_bf  = (unsigned short*)(ws + 100663296);
  unsigned short* wo_bf  = (unsigned short*)(ws + 109051904);
  unsigned short* wte_bf = (unsigned short*)(ws + 25165824);    // alias post-loop [50432][1024]
  float*          nll    = (float*)(ws + 128450560);
  float*          vld    = (float*)(ws + 128466944);

  embed_kernel<<<(M_ROWS * D_DIM + 255) / 256, 256, 0, stream>>>(ctx, wte, wpe, x);

  for (int l = 0; l < L_NUM; ++l) {
    conv_layer_kernel<<<6144, 256, 0, stream>>>(
        w_attn + (size_t)l * 3 * D_DIM * D_DIM, w_proj + (size_t)l * D_DIM * D_DIM,
        w_fc + (size_t)l * 4 * D_DIM * D_DIM, w_out + (size_t)l * D_DIM * 4 * D_DIM,
        wa_bf, wp_bf, wf_bf, wo_bf);
    layernorm_kernel<<<M_ROWS, 256, 0, stream>>>(x, ln1_g + l * D_DIM, ln1_b + l * D_DIM, xn);
    gemm8p<3><<<12 * 16, 512, 0, stream>>>(
        xn, wa_bf, qkv, D_DIM, 3 * D_DIM, 3 * D_DIM, 16, 1);
    flash_attn_kernel<<<dim3(T_LEN / 64, B_NUM * H_NUM), 256, 0, stream>>>(qkv, y);
    mfma_gemm<1><<<dim3(D_DIM / 128, M_ROWS / 128), 256, 0, stream>>>(
        y, wp_bf, x, x, D_DIM, D_DIM, D_DIM);
    layernorm_kernel<<<M_ROWS, 256, 0, stream>>>(x, ln2_g + l * D_DIM, ln2_b + l * D_DIM, xn);
    gemm8p<2><<<16 * 16, 512, 0, stream>>>(
        xn, wf_bf, h, D_DIM, 4 * D_DIM, 4 * D_DIM, 16, 1);
    mfma_gemm<1><<<dim3(D_DIM / 128, M_ROWS / 128), 256, 0, stream>>>(
        h, wo_bf, x, x, 4 * D_DIM, D_DIM, D_DIM);
  }

  layernorm_kernel<<<M_ROWS, 256, 0, stream>>>(x, lnf_g, lnf_b, xn);
  conv_kernel<<<25129, 256, 0, stream>>>(wte, wte_bf, (long)V_SIZE * D_DIM);
  hipMemsetAsync(wte_bf + (size_t)V_SIZE * D_DIM, 0,
                 (size_t)(V_PAD - V_SIZE) * D_DIM * sizeof(unsigned short), stream);
  gemm8p<0><<<197 * 16, 512, 0, stream>>>(
      xn, wte_bf, logits, D_DIM, V_SIZE, V_SIZE, 16, 1);
  loss_rows_kernel<<<M_ROWS, 256, 0, stream>>>(logits, tgt, nll, vld);
  loss_reduce_kernel<<<1, 256, 0, stream>>>(nll, vld, loss);
}

// Round 8
// 3244.829 us; speedup vs baseline: 14.0309x; 1.0610x over previous
//
#include <hip/hip_runtime.h>
#include <cstdint>

#define V_SIZE 50257
#define V_PAD  50432            // 197 * 256
#define NCB    197              // logits col-blocks
#define D_DIM  1024
#define H_NUM  16
#define L_NUM  8
#define T_LEN  1024
#define B_NUM  4
#define HD_DIM 64
#define M_ROWS 4096
#define LN_EPS 1e-5f

typedef __attribute__((ext_vector_type(8))) __bf16 bf16x8;
typedef __attribute__((ext_vector_type(4))) float f32x4;
typedef __attribute__((ext_vector_type(8))) unsigned short u16x8;

__device__ __forceinline__ unsigned short f2bf(float f) {
  unsigned u = __builtin_bit_cast(unsigned, f);
  u += 0x7fffu + ((u >> 16) & 1u);   // RNE
  return (unsigned short)(u >> 16);
}

__device__ __forceinline__ void gload_lds16(const void* g, void* l) {
  typedef const __attribute__((address_space(1))) unsigned int* gp_t;
  typedef __attribute__((address_space(3))) unsigned int* lp_t;
  __builtin_amdgcn_global_load_lds((gp_t)g, (lp_t)l, 16, 0, 0);
}

__device__ __forceinline__ f32x4 mfma16(bf16x8 a, bf16x8 b, f32x4 c) {
  return __builtin_amdgcn_mfma_f32_16x16x32_bf16(a, b, c, 0, 0, 0);
}

#define BARSB() { __builtin_amdgcn_s_barrier(); __builtin_amdgcn_sched_barrier(0); }
#define SCHB()  __builtin_amdgcn_sched_barrier(0)

// ---------------- embedding ----------------
__global__ __launch_bounds__(256) void embed_kernel(const int* __restrict__ ctx,
                                                    const float* __restrict__ wte,
                                                    const float* __restrict__ wpe,
                                                    float* __restrict__ x) {
  int i = blockIdx.x * blockDim.x + threadIdx.x;
  if (i >= M_ROWS * D_DIM) return;
  int bt = i / D_DIM, d = i - bt * D_DIM;
  int t = bt & (T_LEN - 1);
  x[i] = wte[(size_t)ctx[bt] * D_DIM + d] + wpe[(size_t)t * D_DIM + d];
}

// ---------------- fp32 -> bf16 weight conversion ----------------
__global__ __launch_bounds__(256) void conv_layer_kernel(const float* __restrict__ wa,
                                                         const float* __restrict__ wp,
                                                         const float* __restrict__ wf,
                                                         const float* __restrict__ wo,
                                                         unsigned short* __restrict__ oa,
                                                         unsigned short* __restrict__ op,
                                                         unsigned short* __restrict__ of,
                                                         unsigned short* __restrict__ oo) {
  long i = (long)(blockIdx.x * 256 + threadIdx.x) * 8;
  const float* src; unsigned short* dst; long off;
  if (i < 3145728L)      { src = wa; dst = oa; off = i; }
  else if (i < 4194304L) { src = wp; dst = op; off = i - 3145728L; }
  else if (i < 8388608L) { src = wf; dst = of; off = i - 4194304L; }
  else                   { src = wo; dst = oo; off = i - 8388608L; }
  float4 v0 = *(const float4*)(src + off);
  float4 v1 = *(const float4*)(src + off + 4);
  u16x8 o;
  o[0] = f2bf(v0.x); o[1] = f2bf(v0.y); o[2] = f2bf(v0.z); o[3] = f2bf(v0.w);
  o[4] = f2bf(v1.x); o[5] = f2bf(v1.y); o[6] = f2bf(v1.z); o[7] = f2bf(v1.w);
  *(u16x8*)(dst + off) = o;
}

__global__ __launch_bounds__(256) void conv_kernel(const float* __restrict__ in,
                                                   unsigned short* __restrict__ out, long n) {
  long i = (long)(blockIdx.x * 256 + threadIdx.x) * 8;
  if (i >= n) return;
  float4 v0 = *(const float4*)(in + i);
  float4 v1 = *(const float4*)(in + i + 4);
  u16x8 o;
  o[0] = f2bf(v0.x); o[1] = f2bf(v0.y); o[2] = f2bf(v0.z); o[3] = f2bf(v0.w);
  o[4] = f2bf(v1.x); o[5] = f2bf(v1.y); o[6] = f2bf(v1.z); o[7] = f2bf(v1.w);
  *(u16x8*)(out + i) = o;
}

// ---------------- layernorm: fp32 in -> bf16 out ----------------
__global__ __launch_bounds__(256) void layernorm_kernel(const float* __restrict__ x,
                                                        const float* __restrict__ g,
                                                        const float* __restrict__ b,
                                                        unsigned short* __restrict__ o) {
  int r = blockIdx.x;
  int tid = threadIdx.x;
  const float* row = x + (size_t)r * D_DIM;
  float4 v = *(const float4*)(row + tid * 4);
  float s  = v.x + v.y + v.z + v.w;
  float s2 = v.x * v.x + v.y * v.y + v.z * v.z + v.w * v.w;
  #pragma unroll
  for (int off = 32; off; off >>= 1) {
    s  += __shfl_xor(s, off);
    s2 += __shfl_xor(s2, off);
  }
  __shared__ float a1[4], a2[4];
  int w = tid >> 6, lane = tid & 63;
  if (lane == 0) { a1[w] = s; a2[w] = s2; }
  __syncthreads();
  s  = a1[0] + a1[1] + a1[2] + a1[3];
  s2 = a2[0] + a2[1] + a2[2] + a2[3];
  float mu  = s * (1.0f / D_DIM);
  float var = s2 * (1.0f / D_DIM) - mu * mu;
  float rs  = rsqrtf(var + LN_EPS);
  int d = tid * 4;
  float4 gv = *(const float4*)(g + d);
  float4 bv = *(const float4*)(b + d);
  ushort4 ov;
  ov.x = f2bf((v.x - mu) * rs * gv.x + bv.x);
  ov.y = f2bf((v.y - mu) * rs * gv.y + bv.y);
  ov.z = f2bf((v.z - mu) * rs * gv.z + bv.z);
  ov.w = f2bf((v.w - mu) * rs * gv.w + bv.w);
  *(ushort4*)(o + (size_t)r * D_DIM + d) = ov;
}

// ---------------- m97-structure 128x128 bf16 MFMA GEMM (proj/out) ----------
template<int EPI>
__global__ __launch_bounds__(256) void mfma_gemm(const unsigned short* __restrict__ A,
                                                 const unsigned short* __restrict__ W,
                                                 const float* R, void* Cout,
                                                 int K, int ldc, int nreal) {
  __shared__ unsigned short As[128 * 32];
  __shared__ unsigned short Bs[128 * 32];
  const int tid  = threadIdx.x;
  const int wave = tid >> 6, lane = tid & 63;
  const int wr = wave >> 1, wc = wave & 1;
  const long row0 = (long)blockIdx.y * 128;
  const long col0 = (long)blockIdx.x * 128;
  f32x4 acc[4][4] = {};
  const int frow = lane & 15;
  const int fk   = (lane >> 4) * 8;
  const int b0 = wave * 2048 + lane * 16;
  for (int k0 = 0; k0 < K; k0 += 32) {
    #pragma unroll
    for (int c = 0; c < 2; ++c) {
      int b = b0 + c * 1024;
      int r = b >> 6, ke = (b & 63) >> 1;
      gload_lds16(A + (row0 + r) * (long)K + k0 + ke, (char*)As + b);
      gload_lds16(W + (col0 + r) * (long)K + k0 + ke, (char*)Bs + b);
    }
    __syncthreads();
    bf16x8 af[4], bfr[4];
    #pragma unroll
    for (int i = 0; i < 4; ++i)
      af[i] = *(const bf16x8*)(As + (wr * 64 + i * 16 + frow) * 32 + fk);
    #pragma unroll
    for (int j = 0; j < 4; ++j)
      bfr[j] = *(const bf16x8*)(Bs + (wc * 64 + j * 16 + frow) * 32 + fk);
    #pragma unroll
    for (int i = 0; i < 4; ++i)
      #pragma unroll
      for (int j = 0; j < 4; ++j)
        acc[i][j] = mfma16(af[i], bfr[j], acc[i][j]);
    __syncthreads();
  }
  const int crow = (lane >> 4) * 4;
  const int ccol = lane & 15;
  #pragma unroll
  for (int i = 0; i < 4; ++i) {
    #pragma unroll
    for (int r = 0; r < 4; ++r) {
      long row = row0 + wr * 64 + i * 16 + crow + r;
      #pragma unroll
      for (int j = 0; j < 4; ++j) {
        long col = col0 + wc * 64 + j * 16 + ccol;
        float v = acc[i][j][r];
        if (EPI == 1) {
          ((float*)Cout)[row * (long)ldc + col] = v + R[row * (long)ldc + col];
        } else {
          ((float*)Cout)[row * (long)ldc + col] = v;
        }
      }
    }
  }
}

// ---------------- 256x256 software-pipelined bf16 GEMM (qkv/fc/logits) ----------
// Round-7 schedule (kept). EPI==0 additionally computes per-row LSE partials
// over this block's 256-col tile (llo-shfl + LDS cross-wave merge) so the
// loss never re-reads the 823 MB logits buffer.
__device__ __forceinline__ void stage_chunk8(const unsigned short* __restrict__ base,
                                             long rbase, int K, long gk,
                                             char* cb, int tid) {
  #pragma unroll
  for (int j = 0; j < 2; ++j) {
    int db = j * 8192 + tid * 16;
    int lb = db ^ (((db >> 7) & 3) << 4);
    long r = lb >> 6;
    int e = (lb & 63) >> 1;
    gload_lds16(base + (rbase + r) * (long)K + gk + e, cb + db);
  }
}

__device__ __forceinline__ bf16x8 rdfrag(const char* cb, int rr, int lhi) {
  int p = (rr << 6) + (lhi << 4);
  p ^= ((rr >> 1) & 3) << 4;
  return *(const bf16x8*)(cb + p);
}

template<int EPI>
__global__ __launch_bounds__(512, 1) void gemm8p(const unsigned short* __restrict__ A,
                                                 const unsigned short* __restrict__ W,
                                                 void* Cout, int K, int ldc, int nreal,
                                                 int nbx, int xcd,
                                                 float* __restrict__ pmax,
                                                 float* __restrict__ psum) {
  __shared__ char lds[131072];
  const int tid  = threadIdx.x;
  const int lane = tid & 63;
  const int wave = tid >> 6;
  const int wr = wave >> 2, wc = wave & 3;
  const int lhi = lane >> 4, llo = lane & 15;
  int bid = blockIdx.x;
  if (xcd) { int per = (int)gridDim.x >> 3; bid = (bid & 7) * per + (bid >> 3); }
  const int brow = bid % nbx;
  const int bcol = bid / nbx;
  const long row0 = (long)brow * 256;
  const long col0 = (long)bcol * 256;
  char* Ab0 = (char*)lds;
  char* Bb0 = (char*)lds + 65536;
  const int nt = K >> 6;   // nt >= 3 assumed (all uses: nt = 16)

  stage_chunk8(W, col0, K, 0,  Bb0,         tid);
  stage_chunk8(A, row0, K, 0,  Ab0,         tid);
  stage_chunk8(W, col0, K, 32, Bb0 + 16384, tid);
  stage_chunk8(A, row0, K, 32, Ab0 + 16384, tid);
  stage_chunk8(W, col0, K, 64, Bb0 + 32768, tid);
  stage_chunk8(A, row0, K, 64, Ab0 + 32768, tid);
  stage_chunk8(W, col0, K, 96, Bb0 + 49152, tid);
  asm volatile("s_waitcnt vmcnt(10)" ::: "memory");
  BARSB();

  const int arow  = wr * 128 + llo;
  const int brow_ = wc * 64 + llo;

  bf16x8 aa0[4], aa1[4], bb0[4], bb1[4];
  #pragma unroll
  for (int m = 0; m < 4; ++m) aa0[m] = rdfrag(Ab0, arow + m * 16, lhi);
  #pragma unroll
  for (int n = 0; n < 4; ++n) bb0[n] = rdfrag(Bb0, brow_ + n * 16, lhi);

  f32x4 acc[8][4] = {};
  for (int t = 0; t < nt; ++t) {
    char* Ac = Ab0 + (t & 1) * 32768;
    char* Bc = Bb0 + (t & 1) * 32768;
    char* An = Ab0 + ((t + 1) & 1) * 32768;
    char* Bn = Bb0 + ((t + 1) & 1) * 32768;
    // ===== S0
    #pragma unroll
    for (int m = 0; m < 4; ++m) aa1[m] = rdfrag(Ac, arow + 64 + m * 16, lhi);
    asm volatile("s_waitcnt lgkmcnt(4)" ::: "memory");
    SCHB();
    if (t + 1 < nt) stage_chunk8(A, row0, K, (long)(t + 1) * 64 + 32, An + 16384, tid);
    __builtin_amdgcn_s_setprio(1);
    #pragma unroll
    for (int m = 0; m < 4; ++m)
      #pragma unroll
      for (int n = 0; n < 4; ++n)
        acc[m][n] = mfma16(aa0[m], bb0[n], acc[m][n]);
    __builtin_amdgcn_s_setprio(0);
    SCHB();
    if (t < nt - 1) { asm volatile("s_waitcnt vmcnt(8)" ::: "memory"); }
    else            { asm volatile("s_waitcnt vmcnt(0)" ::: "memory"); }
    BARSB();
    // ===== S1
    #pragma unroll
    for (int m = 0; m < 4; ++m) aa0[m] = rdfrag(Ac + 16384, arow + m * 16, lhi);
    #pragma unroll
    for (int n = 0; n < 4; ++n) bb1[n] = rdfrag(Bc + 16384, brow_ + n * 16, lhi);
    asm volatile("s_waitcnt lgkmcnt(8)" ::: "memory");
    SCHB();
    if (t + 2 < nt) stage_chunk8(W, col0, K, (long)(t + 2) * 64, Bc, tid);
    __builtin_amdgcn_s_setprio(1);
    #pragma unroll
    for (int m = 0; m < 4; ++m)
      #pragma unroll
      for (int n = 0; n < 4; ++n)
        acc[m + 4][n] = mfma16(aa1[m], bb0[n], acc[m + 4][n]);
    __builtin_amdgcn_s_setprio(0);
    SCHB();
    BARSB();
    // ===== S2
    #pragma unroll
    for (int m = 0; m < 4; ++m) aa1[m] = rdfrag(Ac + 16384, arow + 64 + m * 16, lhi);
    asm volatile("s_waitcnt lgkmcnt(4)" ::: "memory");
    SCHB();
    if (t + 2 < nt) stage_chunk8(A, row0, K, (long)(t + 2) * 64, Ac, tid);
    __builtin_amdgcn_s_setprio(1);
    #pragma unroll
    for (int m = 0; m < 4; ++m)
      #pragma unroll
      for (int n = 0; n < 4; ++n)
        acc[m][n] = mfma16(aa0[m], bb1[n], acc[m][n]);
    __builtin_amdgcn_s_setprio(0);
    SCHB();
    if (t <= nt - 3)      { asm volatile("s_waitcnt vmcnt(8)" ::: "memory"); }
    else if (t == nt - 2) { asm volatile("s_waitcnt vmcnt(4)" ::: "memory"); }
    else                  { asm volatile("s_waitcnt vmcnt(0)" ::: "memory"); }
    BARSB();
    // ===== S3
    if (t + 1 < nt) {
      #pragma unroll
      for (int m = 0; m < 4; ++m) aa0[m] = rdfrag(An, arow + m * 16, lhi);
      #pragma unroll
      for (int n = 0; n < 4; ++n) bb0[n] = rdfrag(Bn, brow_ + n * 16, lhi);
      asm volatile("s_waitcnt lgkmcnt(8)" ::: "memory");
    } else {
      asm volatile("s_waitcnt lgkmcnt(0)" ::: "memory");
    }
    SCHB();
    if (t + 2 < nt) stage_chunk8(W, col0, K, (long)(t + 2) * 64 + 32, Bc + 16384, tid);
    __builtin_amdgcn_s_setprio(1);
    #pragma unroll
    for (int m = 0; m < 4; ++m)
      #pragma unroll
      for (int n = 0; n < 4; ++n)
        acc[m + 4][n] = mfma16(aa1[m], bb1[n], acc[m + 4][n]);
    __builtin_amdgcn_s_setprio(0);
    SCHB();
    BARSB();
  }

  // ---- epilogue: stores ----
  #pragma unroll
  for (int mi = 0; mi < 8; ++mi) {
    #pragma unroll
    for (int rg = 0; rg < 4; ++rg) {
      long row = row0 + wr * 128 + mi * 16 + lhi * 4 + rg;
      #pragma unroll
      for (int n = 0; n < 4; ++n) {
        long col = col0 + wc * 64 + n * 16 + llo;
        float v = acc[mi][n][rg];
        if (EPI == 0) {
          if (col < nreal) ((float*)Cout)[row * (long)ldc + col] = v;
        } else if (EPI == 2) {
          float gl = 0.5f * v * (1.0f + erff(v * 0.70710678118654752440f));
          ((unsigned short*)Cout)[row * (long)ldc + col] = f2bf(gl);
        } else {
          ((unsigned short*)Cout)[row * (long)ldc + col] = f2bf(v);
        }
      }
    }
  }

  if (EPI == 0) {
    // ---- block-local LSE partials over this 256-col tile (padded cols masked)
    float* red = (float*)lds;   // [256 rows][4 wc][2]
    #pragma unroll
    for (int mi = 0; mi < 8; ++mi) {
      #pragma unroll
      for (int rg = 0; rg < 4; ++rg) {
        float mx = -1e30f;
        #pragma unroll
        for (int n = 0; n < 4; ++n) {
          long col = col0 + wc * 64 + n * 16 + llo;
          if (col < nreal) mx = fmaxf(mx, acc[mi][n][rg]);
        }
        float se = 0.f;
        #pragma unroll
        for (int n = 0; n < 4; ++n) {
          long col = col0 + wc * 64 + n * 16 + llo;
          if (col < nreal) se += __expf(acc[mi][n][rg] - mx);
        }
        #pragma unroll
        for (int off = 1; off < 16; off <<= 1) {
          float om = __shfl_xor(mx, off);
          float os = __shfl_xor(se, off);
          float M = fmaxf(mx, om);
          se = se * __expf(mx - M) + os * __expf(om - M);
          mx = M;
        }
        if (llo == 0) {
          int rloc = wr * 128 + mi * 16 + lhi * 4 + rg;
          red[(rloc * 4 + wc) * 2 + 0] = mx;
          red[(rloc * 4 + wc) * 2 + 1] = se;
        }
      }
    }
    __syncthreads();
    if (tid < 256) {
      float m = red[(tid * 4 + 0) * 2 + 0], s = red[(tid * 4 + 0) * 2 + 1];
      #pragma unroll
      for (int wci = 1; wci < 4; ++wci) {
        float om = red[(tid * 4 + wci) * 2 + 0], os = red[(tid * 4 + wci) * 2 + 1];
        float M = fmaxf(m, om);
        s = s * __expf(m - M) + os * __expf(om - M);
        m = M;
      }
      pmax[(long)bcol * M_ROWS + row0 + tid] = m;
      psum[(long)bcol * M_ROWS + row0 + tid] = s;
    }
  }
}

// ---------------- MFMA flash attention: 128-query blocks, 8 waves ----------------
// grid (T/128, B*H), 512 thr. Wave w owns queries q0+w*16..+15. K/V staged once
// per 64-key tile for all 128 queries (staging roles: tid<256 -> V-transpose,
// tid>=256 -> K rows). Swizzles: byte ^= (row&7)<<4.
__global__ __launch_bounds__(512) void flash_attn_kernel(const unsigned short* __restrict__ qkv,
                                                         unsigned short* __restrict__ y) {
  __shared__ unsigned short Kls[64 * 64];
  __shared__ unsigned short Vtls[64 * 64];
  __shared__ unsigned short Pls[8][16 * 64];
  const int tid = threadIdx.x, wave = tid >> 6, lane = tid & 63;
  const int qt = blockIdx.x;                     // 0..7
  const int h = blockIdx.y & (H_NUM - 1), b = blockIdx.y >> 4;
  const int q0 = qt * 128;
  const int lhi = lane >> 4, llo = lane & 15;

  const int qrow = q0 + wave * 16 + llo;
  const unsigned short* qptr =
      qkv + ((size_t)(b * T_LEN + qrow)) * 3072 + h * HD_DIM + lhi * 8;
  const bf16x8 qa0 = *(const bf16x8*)qptr;
  const bf16x8 qa1 = *(const bf16x8*)(qptr + 32);

  f32x4 o[4] = {};
  float m[4] = {-1e30f, -1e30f, -1e30f, -1e30f};
  float l[4] = {0.f, 0.f, 0.f, 0.f};

  const unsigned short* kg = qkv + (size_t)b * T_LEN * 3072 + D_DIM + h * HD_DIM;
  const unsigned short* vg = kg + D_DIM;

  // staging roles
  const int vs0 = ((tid & 255) >> 3) * 2, vd0 = (tid & 7) * 8;   // tid<256: V
  const int t2 = tid - 256;
  const int krow = (t2 & 255) >> 2, kcol = (t2 & 3) * 16;        // tid>=256: K

  const int ntiles = 2 * qt + 2;
  for (int st = 0; st < ntiles; ++st) {
    const int s0 = st * 64;
    if (tid < 256) {
      const unsigned short* src = vg + (size_t)(s0 + vs0) * 3072 + vd0;
      u16x8 a = *(const u16x8*)src;
      u16x8 c = *(const u16x8*)(src + 3072);
      #pragma unroll
      for (int j = 0; j < 8; ++j) {
        int d = vd0 + j;
        unsigned val = (unsigned)a[j] | ((unsigned)c[j] << 16);
        *(unsigned*)((char*)Vtls + ((d * 128 + vs0 * 2) ^ ((d & 7) << 4))) = val;
      }
    } else {
      const unsigned short* src = kg + (size_t)(s0 + krow) * 3072 + kcol;
      u16x8 a = *(const u16x8*)src;
      u16x8 c = *(const u16x8*)(src + 8);
      int base = krow * 128 + kcol * 2;
      int sw = (krow & 7) << 4;
      *(u16x8*)((char*)Kls + ((base) ^ sw))      = a;
      *(u16x8*)((char*)Kls + ((base + 16) ^ sw)) = c;
    }
    __syncthreads();

    f32x4 s_acc[4] = {};
    #pragma unroll
    for (int kt = 0; kt < 4; ++kt) {
      int kr = kt * 16 + llo;
      int sw = (kr & 7) << 4;
      bf16x8 kb0 = *(const bf16x8*)((char*)Kls + ((kr * 128 + lhi * 16) ^ sw));
      bf16x8 kb1 = *(const bf16x8*)((char*)Kls + ((kr * 128 + 64 + lhi * 16) ^ sw));
      s_acc[kt] = mfma16(qa0, kb0, s_acc[kt]);
      s_acc[kt] = mfma16(qa1, kb1, s_acc[kt]);
    }

    float p[4][4];
    float tmax[4] = {-1e30f, -1e30f, -1e30f, -1e30f};
    const int qg = q0 + wave * 16 + lhi * 4;
    #pragma unroll
    for (int kt = 0; kt < 4; ++kt) {
      int ks = s0 + kt * 16 + llo;
      #pragma unroll
      for (int r = 0; r < 4; ++r) {
        float sv = (ks <= qg + r) ? s_acc[kt][r] * 0.125f : -1e30f;
        p[kt][r] = sv;
        tmax[r] = fmaxf(tmax[r], sv);
      }
    }
    #pragma unroll
    for (int r = 0; r < 4; ++r) {
      #pragma unroll
      for (int off = 1; off < 16; off <<= 1)
        tmax[r] = fmaxf(tmax[r], __shfl_xor(tmax[r], off));
      float mn = fmaxf(m[r], tmax[r]);
      float corr = __expf(m[r] - mn);
      m[r] = mn;
      float ps = 0.f;
      #pragma unroll
      for (int kt = 0; kt < 4; ++kt) {
        p[kt][r] = __expf(p[kt][r] - mn);
        ps += p[kt][r];
      }
      #pragma unroll
      for (int off = 1; off < 16; off <<= 1)
        ps += __shfl_xor(ps, off);
      l[r] = l[r] * corr + ps;
      #pragma unroll
      for (int dt = 0; dt < 4; ++dt) o[dt][r] *= corr;
    }

    unsigned short* pw = Pls[wave];
    #pragma unroll
    for (int r = 0; r < 4; ++r) {
      int q = lhi * 4 + r;
      int sw = (q & 7) << 4;
      #pragma unroll
      for (int kt = 0; kt < 4; ++kt) {
        int k = kt * 16 + llo;
        *(unsigned short*)((char*)pw + ((q * 128 + k * 2) ^ sw)) = f2bf(p[kt][r]);
      }
    }
    asm volatile("s_waitcnt lgkmcnt(0)" ::: "memory");

    int psw = (llo & 7) << 4;
    bf16x8 pa0 = *(const bf16x8*)((char*)pw + ((llo * 128 + lhi * 16) ^ psw));
    bf16x8 pa1 = *(const bf16x8*)((char*)pw + ((llo * 128 + 64 + lhi * 16) ^ psw));
    #pragma unroll
    for (int dt = 0; dt < 4; ++dt) {
      int vr = dt * 16 + llo;
      int sw = (vr & 7) << 4;
      bf16x8 vb0 = *(const bf16x8*)((char*)Vtls + ((vr * 128 + lhi * 16) ^ sw));
      bf16x8 vb1 = *(const bf16x8*)((char*)Vtls + ((vr * 128 + 64 + lhi * 16) ^ sw));
      o[dt] = mfma16(pa0, vb0, o[dt]);
      o[dt] = mfma16(pa1, vb1, o[dt]);
    }
    __syncthreads();
  }

  #pragma unroll
  for (int r = 0; r < 4; ++r) {
    long row = q0 + wave * 16 + lhi * 4 + r;
    float inv = 1.0f / l[r];
    #pragma unroll
    for (int dt = 0; dt < 4; ++dt) {
      long col = h * HD_DIM + dt * 16 + llo;
      y[(row + (size_t)b * T_LEN) * D_DIM + col] = f2bf(o[dt][r] * inv);
    }
  }
}

// ---------------- loss: merge per-colblock LSE partials ----------------
__global__ __launch_bounds__(256) void loss_combine_kernel(const float* __restrict__ pmax,
                                                           const float* __restrict__ psum,
                                                           const float* __restrict__ logits,
                                                           const int* __restrict__ tgt,
                                                           float* __restrict__ nll,
                                                           float* __restrict__ vld) {
  int r = blockIdx.x * 256 + threadIdx.x;
  float m = pmax[r], s = psum[r];
  for (int cb = 1; cb < NCB; ++cb) {
    float om = pmax[(long)cb * M_ROWS + r];
    float os = psum[(long)cb * M_ROWS + r];
    float M = fmaxf(m, om);
    s = s * __expf(m - M) + os * __expf(om - M);
    m = M;
  }
  int tg = tgt[r];
  if (tg != -1) { nll[r] = m + logf(s) - logits[(size_t)r * V_SIZE + tg]; vld[r] = 1.0f; }
  else          { nll[r] = 0.f;                                           vld[r] = 0.f; }
}

__global__ __launch_bounds__(256) void loss_reduce_kernel(const float* __restrict__ nll,
                                                          const float* __restrict__ vld,
                                                          float* __restrict__ out) {
  int tid = threadIdx.x;
  float s = 0.f, c = 0.f;
  for (int i = tid; i < M_ROWS; i += 256) { s += nll[i]; c += vld[i]; }
  #pragma unroll
  for (int off = 32; off; off >>= 1) { s += __shfl_xor(s, off); c += __shfl_xor(c, off); }
  __shared__ float s1[4], s2[4];
  int w = tid >> 6, lane = tid & 63;
  if (lane == 0) { s1[w] = s; s2[w] = c; }
  __syncthreads();
  if (tid == 0) {
    s = s1[0] + s1[1] + s1[2] + s1[3];
    c = s2[0] + s2[1] + s2[2] + s2[3];
    out[0] = s / fmaxf(c, 1.0f);
  }
}

extern "C" void kernel_launch(void* const* d_in, const int* in_sizes, int n_in,
                              void* d_out, int out_size, void* d_ws, size_t ws_size,
                              hipStream_t stream) {
  const int*   ctx    = (const int*)d_in[0];
  const int*   tgt    = (const int*)d_in[1];
  const float* wte    = (const float*)d_in[2];
  const float* wpe    = (const float*)d_in[3];
  const float* ln1_g  = (const float*)d_in[4];
  const float* ln1_b  = (const float*)d_in[5];
  const float* w_attn = (const float*)d_in[6];
  const float* w_proj = (const float*)d_in[7];
  const float* ln2_g  = (const float*)d_in[8];
  const float* ln2_b  = (const float*)d_in[9];
  const float* w_fc   = (const float*)d_in[10];
  const float* w_out  = (const float*)d_in[11];
  const float* lnf_g  = (const float*)d_in[12];
  const float* lnf_b  = (const float*)d_in[13];

  float* outp   = (float*)d_out;
  float* logits = outp;
  float* loss   = outp + (size_t)M_ROWS * V_SIZE;

  // ---- workspace layout (bytes), max ~134.9 MB ----
  char* ws = (char*)d_ws;
  float*          x      = (float*)(ws + 0);                    // fp32 [4096][1024]
  unsigned short* xn     = (unsigned short*)(ws + 16777216);    // bf16 [4096][1024]
  unsigned short* qkv    = (unsigned short*)(ws + 25165824);    // bf16 [4096][3072]
  unsigned short* y      = (unsigned short*)(ws + 50331648);    // bf16 [4096][1024]
  unsigned short* h      = (unsigned short*)(ws + 58720256);    // bf16 [4096][4096]
  unsigned short* wa_bf  = (unsigned short*)(ws + 92274688);
  unsigned short* wp_bf  = (unsigned short*)(ws + 98566144);
  unsigned short* wf_bf  = (unsigned short*)(ws + 100663296);
  unsigned short* wo_bf  = (unsigned short*)(ws + 109051904);
  unsigned short* wte_bf = (unsigned short*)(ws + 25165824);    // alias post-loop [50432][1024]
  float*          nll    = (float*)(ws + 128450560);
  float*          vld    = (float*)(ws + 128466944);
  float*          pmax   = (float*)(ws + 128483328);            // [197][4096] fp32
  float*          psum   = (float*)(ws + 131710976);            // [197][4096] fp32

  embed_kernel<<<(M_ROWS * D_DIM + 255) / 256, 256, 0, stream>>>(ctx, wte, wpe, x);

  for (int l = 0; l < L_NUM; ++l) {
    conv_layer_kernel<<<6144, 256, 0, stream>>>(
        w_attn + (size_t)l * 3 * D_DIM * D_DIM, w_proj + (size_t)l * D_DIM * D_DIM,
        w_fc + (size_t)l * 4 * D_DIM * D_DIM, w_out + (size_t)l * D_DIM * 4 * D_DIM,
        wa_bf, wp_bf, wf_bf, wo_bf);
    layernorm_kernel<<<M_ROWS, 256, 0, stream>>>(x, ln1_g + l * D_DIM, ln1_b + l * D_DIM, xn);
    gemm8p<3><<<12 * 16, 512, 0, stream>>>(
        xn, wa_bf, qkv, D_DIM, 3 * D_DIM, 3 * D_DIM, 16, 1, nullptr, nullptr);
    flash_attn_kernel<<<dim3(T_LEN / 128, B_NUM * H_NUM), 512, 0, stream>>>(qkv, y);
    mfma_gemm<1><<<dim3(D_DIM / 128, M_ROWS / 128), 256, 0, stream>>>(
        y, wp_bf, x, x, D_DIM, D_DIM, D_DIM);
    layernorm_kernel<<<M_ROWS, 256, 0, stream>>>(x, ln2_g + l * D_DIM, ln2_b + l * D_DIM, xn);
    gemm8p<2><<<16 * 16, 512, 0, stream>>>(
        xn, wf_bf, h, D_DIM, 4 * D_DIM, 4 * D_DIM, 16, 1, nullptr, nullptr);
    mfma_gemm<1><<<dim3(D_DIM / 128, M_ROWS / 128), 256, 0, stream>>>(
        h, wo_bf, x, x, 4 * D_DIM, D_DIM, D_DIM);
  }

  layernorm_kernel<<<M_ROWS, 256, 0, stream>>>(x, lnf_g, lnf_b, xn);
  conv_kernel<<<25129, 256, 0, stream>>>(wte, wte_bf, (long)V_SIZE * D_DIM);
  hipMemsetAsync(wte_bf + (size_t)V_SIZE * D_DIM, 0,
                 (size_t)(V_PAD - V_SIZE) * D_DIM * sizeof(unsigned short), stream);
  gemm8p<0><<<NCB * 16, 512, 0, stream>>>(
      xn, wte_bf, logits, D_DIM, V_SIZE, V_SIZE, 16, 1, pmax, psum);
  loss_combine_kernel<<<M_ROWS / 256, 256, 0, stream>>>(pmax, psum, logits, tgt, nll, vld);
  loss_reduce_kernel<<<1, 256, 0, stream>>>(nll, vld, loss);
}